// Round 10
// baseline (6365.627 us; speedup 1.0000x reference)
//
#include <hip/hip_runtime.h>
#include <hip/hip_fp16.h>

typedef _Float16 f16;
typedef f16 f16x8 __attribute__((ext_vector_type(8)));
typedef f16 f16x4 __attribute__((ext_vector_type(4)));
typedef float f32x4 __attribute__((ext_vector_type(4)));
typedef float f32x16 __attribute__((ext_vector_type(16)));

#define B_ 64
#define T_ 512
#define I_ 256
#define O_ 1024
#define M_ 8
#define IM_ 2048
#define NRECB 128
#define NB 192
#define THREADS 256

// ws layout (bytes)
#define OFF_X16 8192ull
#define OFF_XP3 16785408ull     // 3 x [B][IM] f16 (canonical, triple buffer)
#define OFF_H2  17571840ull     // 2 x [B][O] f16 (canonical)
#define OFF_REP 17833984ull     // 8 XCDs x 2 parities x (xp 256K + h 128K)
#define REP_XCD 786432ull
#define REP_PAR 393216ull
#define REP_H   262144ull

// barrier uint indices (64B-separated lines)
#define LEAFA(i) ((i) * 16)
#define CENTA    128
#define FLAGA(i) (192 + (i) * 16)
#define LEAFB(i) (320 + (i) * 16)
#define CENTB    448
#define FLAGB(i) (512 + (i) * 16)
#define REGC     640
#define NR_(i)   (656 + (i) * 16)
#define NA_(i)   (784 + (i) * 16)
#define XBX_(i)  (912 + (i) * 16)
#define XBH_(i)  (1040 + (i) * 16)

// LDS layout
#define CMB_REC 147456
#define XPRAW   81920
#define CMB_ACT 114688
#define LSE_O   126976
#define PART_O  128000
#define GATE_O  129024
#define META_O  159744
#define SMEM_SZ 159808

#define WAITV(N) asm volatile("s_waitcnt vmcnt(" #N ")" ::: "memory")
#define LGKM0    asm volatile("s_waitcnt lgkmcnt(0)" ::: "memory")
#define SCHEDB   __builtin_amdgcn_sched_barrier(0)
#define BARRIER  __builtin_amdgcn_s_barrier()

// 8 x 16B plain cached loads, 32B stride (read-only x16 input)
#define ISSUE_AX(BUF, P) asm volatile( \
    "global_load_dwordx4 %0, %8, off\n\t" \
    "global_load_dwordx4 %1, %8, off offset:32\n\t" \
    "global_load_dwordx4 %2, %8, off offset:64\n\t" \
    "global_load_dwordx4 %3, %8, off offset:96\n\t" \
    "global_load_dwordx4 %4, %8, off offset:128\n\t" \
    "global_load_dwordx4 %5, %8, off offset:160\n\t" \
    "global_load_dwordx4 %6, %8, off offset:192\n\t" \
    "global_load_dwordx4 %7, %8, off offset:224" \
    : "=&v"(abuf[BUF][0]), "=&v"(abuf[BUF][1]), "=&v"(abuf[BUF][2]), "=&v"(abuf[BUF][3]), \
      "=&v"(abuf[BUF][4]), "=&v"(abuf[BUF][5]), "=&v"(abuf[BUF][6]), "=&v"(abuf[BUF][7]) \
    : "v"(P) : "memory")

// 8 x 16B sc0-only loads (L1-bypass, hit XCD-local L2): replica state reads
#define ISSUE_A0(BUF, P) asm volatile( \
    "global_load_dwordx4 %0, %8, off sc0\n\t" \
    "global_load_dwordx4 %1, %8, off offset:32 sc0\n\t" \
    "global_load_dwordx4 %2, %8, off offset:64 sc0\n\t" \
    "global_load_dwordx4 %3, %8, off offset:96 sc0\n\t" \
    "global_load_dwordx4 %4, %8, off offset:128 sc0\n\t" \
    "global_load_dwordx4 %5, %8, off offset:160 sc0\n\t" \
    "global_load_dwordx4 %6, %8, off offset:192 sc0\n\t" \
    "global_load_dwordx4 %7, %8, off offset:224 sc0" \
    : "=&v"(abuf[BUF][0]), "=&v"(abuf[BUF][1]), "=&v"(abuf[BUF][2]), "=&v"(abuf[BUF][3]), \
      "=&v"(abuf[BUF][4]), "=&v"(abuf[BUF][5]), "=&v"(abuf[BUF][6]), "=&v"(abuf[BUF][7]) \
    : "v"(P) : "memory")

// 8 x 16B sc0-only loads from 8 independent addresses
#define ISSUE8P0(ARR, P0,P1,P2,P3,P4,P5,P6,P7) asm volatile( \
    "global_load_dwordx4 %0, %8, off sc0\n\t" \
    "global_load_dwordx4 %1, %9, off sc0\n\t" \
    "global_load_dwordx4 %2, %10, off sc0\n\t" \
    "global_load_dwordx4 %3, %11, off sc0\n\t" \
    "global_load_dwordx4 %4, %12, off sc0\n\t" \
    "global_load_dwordx4 %5, %13, off sc0\n\t" \
    "global_load_dwordx4 %6, %14, off sc0\n\t" \
    "global_load_dwordx4 %7, %15, off sc0" \
    : "=&v"((ARR)[0]), "=&v"((ARR)[1]), "=&v"((ARR)[2]), "=&v"((ARR)[3]), \
      "=&v"((ARR)[4]), "=&v"((ARR)[5]), "=&v"((ARR)[6]), "=&v"((ARR)[7]) \
    : "v"(P0), "v"(P1), "v"(P2), "v"(P3), "v"(P4), "v"(P5), "v"(P6), "v"(P7) \
    : "memory")

// one chunk: counted wait (+sched fence), 8 MFMA
#define CH(I, WN) do { \
    WAITV(WN); SCHEDB; \
    _Pragma("unroll") \
    for (int kb = 0; kb < 8; ++kb) { \
        f16x8 bf = *(const f16x8*)(smem + addrB[kb] + (I) * 256); \
        if (kb & 1) acc1 = __builtin_amdgcn_mfma_f32_32x32x16_f16(abuf[I][kb], bf, acc1, 0, 0, 0); \
        else        acc0 = __builtin_amdgcn_mfma_f32_32x32x16_f16(abuf[I][kb], bf, acc0, 0, 0, 0); \
    } \
} while (0)

__device__ __forceinline__ void st_coh_h(f16* p, float vf) {
    union { f16 h; short s; } u; u.h = (f16)vf;
    asm volatile("global_store_short %0, %1, off sc0 sc1" :: "v"(p), "v"((int)u.s) : "memory");
}

__device__ __forceinline__ float fast_tanh(float x) {
    float e = __expf(2.f * x);
    return 1.f - 2.f / (e + 1.f);
}

__device__ __forceinline__ unsigned ld_rlx(unsigned* p) {
    return __hip_atomic_load(p, __ATOMIC_RELAXED, __HIP_MEMORY_SCOPE_AGENT);
}
__device__ __forceinline__ unsigned rmw_add(unsigned* p) {
    return __hip_atomic_fetch_add(p, 1u, __ATOMIC_RELAXED, __HIP_MEMORY_SCOPE_AGENT);
}

__device__ __forceinline__ void post_flags(unsigned* bar, int base, unsigned v) {
    #pragma unroll
    for (int i = 0; i < 8; ++i) {
        unsigned* rp = &bar[base + i * 16];
        asm volatile("global_store_dword %0, %1, off sc0 sc1" :: "v"(rp), "v"(v) : "memory");
    }
}

__device__ __forceinline__ void arriveA(unsigned* bar, int blk, int t) {
    unsigned old = rmw_add(&bar[LEAFA(blk & 7)]);
    if (old % 16u == 15u) {
        unsigned r = rmw_add(&bar[CENTA]);
        if ((r & 7u) == 7u) post_flags(bar, FLAGA(0), (unsigned)(t + 1));
    }
}
__device__ __forceinline__ void arriveB(unsigned* bar, int a, int t) {
    unsigned old = rmw_add(&bar[LEAFB(a & 7)]);
    if ((old & 7u) == 7u) {
        unsigned r = rmw_add(&bar[CENTB]);
        if ((r & 7u) == 7u) post_flags(bar, FLAGB(0), (unsigned)(t + 1));
    }
}

// copy nslices of 16KB (stride c) from canonical (sc1, fabric) to XCD replica
// (plain stores -> dirty in local L2; consumers on same XCD read with sc0)
__device__ __forceinline__ void copy_slices(const char* src, char* dst,
                                            int r, int c, int nslices, int tid) {
    for (int s = r; s < nslices; s += c) {
        const char* p0 = src + (size_t)s * 16384 + tid * 16;
        char* d0 = dst + (size_t)s * 16384 + tid * 16;
        f16x8 v0, v1, v2, v3;
        asm volatile(
            "global_load_dwordx4 %0, %4, off sc0 sc1\n\t"
            "global_load_dwordx4 %1, %5, off sc0 sc1\n\t"
            "global_load_dwordx4 %2, %6, off sc0 sc1\n\t"
            "global_load_dwordx4 %3, %7, off sc0 sc1"
            : "=&v"(v0), "=&v"(v1), "=&v"(v2), "=&v"(v3)
            : "v"(p0), "v"(p0 + 4096), "v"(p0 + 8192), "v"(p0 + 12288)
            : "memory");
        WAITV(0); SCHEDB;
        *(f16x8*)(d0) = v0;
        *(f16x8*)(d0 + 4096) = v1;
        *(f16x8*)(d0 + 8192) = v2;
        *(f16x8*)(d0 + 12288) = v3;
    }
}

// init: zero barrier region, convert x [B,T,I] f32 -> x16 [T,B,I] f16, zero state
__global__ void init_kernel(const float* __restrict__ x, char* __restrict__ ws) {
    const int gid = blockIdx.x * 256 + threadIdx.x;
    if (blockIdx.x == 0) {
        for (int i = threadIdx.x; i < 2048; i += 256) ((unsigned*)ws)[i] = 0u;
    }
    f16* x16 = (f16*)(ws + OFF_X16);
    const int NQ = T_ * B_ * (I_ / 4);
    for (int q = gid; q < NQ; q += 256 * 256) {
        int t = q >> 12;
        int rem = q & 4095;
        int b = rem >> 6;
        int k4 = rem & 63;
        f32x4 v = *(const f32x4*)(x + ((size_t)b * T_ + t) * I_ + k4 * 4);
        f16x4 h;
        h[0] = (f16)v[0]; h[1] = (f16)v[1]; h[2] = (f16)v[2]; h[3] = (f16)v[3];
        *(f16x4*)(x16 + ((size_t)t * B_ + b) * I_ + k4 * 4) = h;
    }
    f16x8 z = {0, 0, 0, 0, 0, 0, 0, 0};
    f16* xp0 = (f16*)(ws + OFF_XP3);
    for (int e = gid * 8; e < B_ * IM_; e += 256 * 256 * 8) *(f16x8*)(xp0 + e) = z;
    f16* h0 = (f16*)(ws + OFF_H2);
    for (int e = gid * 8; e < B_ * O_; e += 256 * 256 * 8) *(f16x8*)(h0 + e) = z;
}

__global__ __launch_bounds__(THREADS, 1) void cwrnn_kernel(
    const float* __restrict__ x, const float* __restrict__ W_in, const float* __restrict__ b_in,
    const float* __restrict__ W_h, const float* __restrict__ W_ir, const float* __restrict__ b_ir,
    const float* __restrict__ W_hr, const float* __restrict__ periods, const float* __restrict__ shifts,
    float* __restrict__ out, char* __restrict__ ws)
{
    __shared__ __align__(16) char smem[SMEM_SZ];

    unsigned* bar = (unsigned*)ws;
    const int blk = blockIdx.x, tid = threadIdx.x;
    const int lane = tid & 63, w = tid >> 6;
    const int col = lane & 31, g = lane >> 5;

    float* ys = out;
    float* hfin = out + (size_t)B_ * T_ * O_;
    float* ps = hfin + (size_t)B_ * O_;

    // ---- per-XCD registration: learn true XCD, rank, counts ----
    int* meta = (int*)(smem + META_O);
    if (tid == 0) {
        unsigned xcdv;
        asm volatile("s_getreg_b32 %0, hwreg(HW_REG_XCC_ID)" : "=s"(xcdv));
        xcdv &= 7u;
        unsigned rnk;
        if (blk < NRECB) rnk = rmw_add(&bar[NR_(xcdv)]);
        else             rnk = rmw_add(&bar[NA_(xcdv)]);
        WAITV(0);                 // NR/NA RMW complete at L3 before REGC add
        rmw_add(&bar[REGC]);
        while (ld_rlx(&bar[REGC]) < (unsigned)NB) __builtin_amdgcn_s_sleep(8);
        meta[0] = (int)xcdv;
        meta[1] = (int)rnk;
        meta[2] = (int)ld_rlx(&bar[NR_(xcdv)]);
        meta[3] = (int)ld_rlx(&bar[NA_(xcdv)]);
    }
    LGKM0; BARRIER;
    const int xcd = meta[0], rank = meta[1], nR = meta[2], nA = meta[3];
    const bool isREC = (blk < NRECB);
    const bool doXP = isREC || (nR == 0);
    const bool doH  = (!isREC) || (nA == 0);
    const int cX = (nR > 0) ? nR : nA;
    const int cH = (nA > 0) ? nA : nR;
    const bool needFbT = isREC && (nA == 0);
    char* rep = ws + OFF_REP + (size_t)xcd * REP_XCD;
    unsigned* xbX = &bar[XBX_(xcd)];
    unsigned* xbH = &bar[XBH_(xcd)];
    f16* const xpB = (f16*)(ws + OFF_XP3);
    f16* h2 = (f16*)(ws + OFF_H2);

    if (isREC) {
        // ========== REC: block = (col-group cg, row-half rh); 32 rows x 32 cols ==========
        const int cg = blk >> 1, rh = blk & 1;
        const int j0 = cg * 32;
        const int row0 = rh * 32;
        const int arow = row0 + col;
        {   // stage W2 = [W_ir | W_hr] rows j0..j0+31 into swizzled LDS (once)
            const int j = tid & 31;
            const float* ra = W_ir + (size_t)(j0 + j) * I_;
            const float* rb = W_hr + (size_t)(j0 + j) * IM_ - 256;
            for (int u = (tid >> 5); u < 288; u += 8) {
                int k0 = u * 8;
                const float* s = (k0 < 256) ? (ra + k0) : (rb + k0);
                f32x4 lo = *(const f32x4*)s;
                f32x4 hi = *(const f32x4*)(s + 4);
                f16x8 v;
                #pragma unroll
                for (int e = 0; e < 4; ++e) { v[e] = (f16)lo[e]; v[e + 4] = (f16)hi[e]; }
                *(f16x8*)(smem + j * 4608 + ((u ^ (j & 15)) << 4)) = v;
            }
        }
        const float bir = b_ir[j0 + col];
        LGKM0; BARRIER;

        const int c0k = (w == 0) ? 0 : (w == 1) ? 5 : (w == 2) ? 10 : 14;
        int addrB[8];
        #pragma unroll
        for (int kb = 0; kb < 8; ++kb)
            addrB[kb] = col * 4608 + ((((kb << 1) + g) ^ (col & 15)) << 4) + c0k * 256;

        const char* xrow0 = (const char*)(ws + OFF_X16) + (size_t)arow * 512 + g * 16;
        unsigned* fA = &bar[FLAGA(blk & 7)];
        unsigned* fB = &bar[FLAGB(blk & 7)];

        for (int t = 0; t < T_; ++t) {
            if (tid == 0) {
                while (1) {
                    int fa = (int)ld_rlx(fA);
                    int fb = (int)ld_rlx(fB);
                    if (fa >= t && fb >= t - 1 && (!needFbT || fb >= t)) break;
                    __builtin_amdgcn_s_sleep(2);
                }
            }
            BARRIER;
            const int bi = t % 3;
            int bn = bi + 1; if (bn == 3) bn = 0;
            char* repP = rep + (size_t)(t & 1) * REP_PAR;
            // ---- multicast copy: canonical -> XCD-local replica ----
            if (doXP) copy_slices((const char*)(xpB + (size_t)bi * B_ * IM_), repP, rank, cX, 16, tid);
            if (doH)  copy_slices((const char*)(h2 + (size_t)(t & 1) * B_ * O_), repP + REP_H, rank, cH, 8, tid);
            WAITV(0);
            BARRIER;
            if (tid == 0) {
                if (doXP) rmw_add(xbX);
                if (doH)  rmw_add(xbH);
            }
            if (t < T_ - 1) {
                if (tid == 0) {
                    unsigned tgt = (unsigned)(cX * (t + 1));
                    while (ld_rlx(xbX) < tgt) __builtin_amdgcn_s_sleep(1);
                }
                BARRIER;
                f16* xpnxt = xpB + (size_t)bn * B_ * IM_;
                const char* sprow = (const char*)repP + (size_t)arow * 4096 + g * 16 - 512;
                const char* xrow = xrow0 + (size_t)t * 32768;

                f16x8 abuf[5][8];
                f32x16 acc0, acc1;
                #pragma unroll
                for (int r = 0; r < 16; ++r) { acc0[r] = 0.f; acc1[r] = 0.f; }

                if (w == 0) {
                    ISSUE_AX(0, xrow); ISSUE_AX(1, (xrow + 256));
                    ISSUE_A0(2, (sprow + 2 * 256)); ISSUE_A0(3, (sprow + 3 * 256)); ISSUE_A0(4, (sprow + 4 * 256));
                    CH(0, 32); CH(1, 24); CH(2, 16); CH(3, 8); CH(4, 0);
                } else if (w == 1) {
                    ISSUE_A0(0, (sprow + 5 * 256)); ISSUE_A0(1, (sprow + 6 * 256)); ISSUE_A0(2, (sprow + 7 * 256));
                    ISSUE_A0(3, (sprow + 8 * 256)); ISSUE_A0(4, (sprow + 9 * 256));
                    CH(0, 32); CH(1, 24); CH(2, 16); CH(3, 8); CH(4, 0);
                } else if (w == 2) {
                    ISSUE_A0(0, (sprow + 10 * 256)); ISSUE_A0(1, (sprow + 11 * 256));
                    ISSUE_A0(2, (sprow + 12 * 256)); ISSUE_A0(3, (sprow + 13 * 256));
                    CH(0, 24); CH(1, 16); CH(2, 8); CH(3, 0);
                } else {
                    ISSUE_A0(0, (sprow + 14 * 256)); ISSUE_A0(1, (sprow + 15 * 256));
                    ISSUE_A0(2, (sprow + 16 * 256)); ISSUE_A0(3, (sprow + 17 * 256));
                    CH(0, 24); CH(1, 16); CH(2, 8); CH(3, 0);
                }

                f32x16 accS;
                #pragma unroll
                for (int r = 0; r < 16; ++r) accS[r] = acc0[r] + acc1[r];
                if (w > 0) {
                    char* cb = smem + CMB_REC + (w - 1) * 4096 + lane * 16;
                    #pragma unroll
                    for (int q = 0; q < 4; ++q) {
                        f32x4 v = { accS[q*4+0], accS[q*4+1], accS[q*4+2], accS[q*4+3] };
                        *(f32x4*)(cb + q * 1024) = v;
                    }
                }
                LGKM0; BARRIER;
                if (w == 0) {
                    #pragma unroll
                    for (int wv = 0; wv < 3; ++wv) {
                        const char* cb = smem + CMB_REC + wv * 4096 + lane * 16;
                        #pragma unroll
                        for (int q = 0; q < 4; ++q) {
                            f32x4 v = *(const f32x4*)(cb + q * 1024);
                            accS[q*4+0] += v[0]; accS[q*4+1] += v[1];
                            accS[q*4+2] += v[2]; accS[q*4+3] += v[3];
                        }
                    }
                    #pragma unroll
                    for (int r = 0; r < 16; ++r) {
                        int rloc = (r & 3) + ((r >> 2) << 3) + (g << 2);
                        st_coh_h(xpnxt + (size_t)(row0 + rloc) * IM_ + j0 + col, fast_tanh(accS[r] + bir));
                    }
                }
                WAITV(0);
            }
            BARRIER;
            if (tid == 0) arriveA(bar, blk, t);
        }
    } else {
        // ========== ACT: block = (col-group colg, row-half rh); 32 rows x 32 cols ==========
        const int a = blk - NRECB;
        const int colg = a >> 1, rh = a & 1;
        const int m = colg >> 2;
        const int o0 = colg * 32;
        const int row0 = rh * 32;
        const int arow = row0 + col;
        {   // stage W1 = [W_in | W_h] rows o0..o0+31
            const int j = tid & 31;
            const float* ra = W_in + (size_t)(o0 + j) * I_;
            const float* rb = W_h + (size_t)(o0 + j) * O_ - 256;
            for (int u = (tid >> 5); u < 160; u += 8) {
                int k0 = u * 8;
                const float* s = (k0 < 256) ? (ra + k0) : (rb + k0);
                f32x4 lo = *(const f32x4*)s;
                f32x4 hi = *(const f32x4*)(s + 4);
                f16x8 v;
                #pragma unroll
                for (int e = 0; e < 4; ++e) { v[e] = (f16)lo[e]; v[e + 4] = (f16)hi[e]; }
                *(f16x8*)(smem + j * 2560 + ((u ^ (j & 15)) << 4)) = v;
            }
        }
        const float bin = b_in[o0 + col];
        const float per = periods[m], shf = shifts[m];
        LGKM0; BARRIER;

        const int c0k = (w == 0) ? 0 : (w == 1) ? 3 : (w == 2) ? 6 : 8;
        int addrB[8];
        #pragma unroll
        for (int kb = 0; kb < 8; ++kb)
            addrB[kb] = col * 2560 + ((((kb << 1) + g) ^ (col & 15)) << 4) + c0k * 256;

        char* xp_raw = smem + XPRAW;
        float* lse_lds = (float*)(smem + LSE_O);
        float* part_lds = (float*)(smem + PART_O);
        float* gate_lds = (float*)(smem + GATE_O);

        const char* xrow0 = (const char*)(ws + OFF_X16) + (size_t)arow * 512 + g * 16;
        unsigned* fA = &bar[FLAGA(a & 7)];
        unsigned* fB = &bar[FLAGB(a & 7)];
        float hreg[16];
        #pragma unroll
        for (int r = 0; r < 16; ++r) hreg[r] = 0.f;

        const int s_ = tid - 128;
        const int cg2 = s_ & 31;
        const int r0s = (s_ >> 5) << 4;

        for (int t = 0; t < T_; ++t) {
            if (tid == 0) {
                while (1) {
                    int fa = (int)ld_rlx(fA);
                    int fb = (int)ld_rlx(fB);
                    if (fa >= t && fb >= t) break;
                    __builtin_amdgcn_s_sleep(2);
                }
            }
            BARRIER;
            const int bi = t % 3;
            char* repP = rep + (size_t)(t & 1) * REP_PAR;
            // ---- multicast copy ----
            if (doXP) copy_slices((const char*)(xpB + (size_t)bi * B_ * IM_), repP, rank, cX, 16, tid);
            if (doH)  copy_slices((const char*)(h2 + (size_t)(t & 1) * B_ * O_), repP + REP_H, rank, cH, 8, tid);
            WAITV(0);
            BARRIER;
            if (tid == 0) {
                if (doXP) rmw_add(xbX);
                if (doH)  rmw_add(xbH);
                unsigned tX = (unsigned)(cX * (t + 1)), tH = (unsigned)(cH * (t + 1));
                while (ld_rlx(xbX) < tX || ld_rlx(xbH) < tH) __builtin_amdgcn_s_sleep(1);
            }
            BARRIER;
            f16* hnxt = h2 + (size_t)((t + 1) & 1) * B_ * O_;
            const char* sprow = (const char*)repP + REP_H + (size_t)arow * 2048 + g * 16 - 512;
            const char* xrow = xrow0 + (size_t)t * 32768;
            f16x8 abuf[3][8];
            f16x8 sregA[8], sregB[8];
            f32x16 acc0, acc1;
            #pragma unroll
            for (int r = 0; r < 16; ++r) { acc0[r] = 0.f; acc1[r] = 0.f; }

            if (w == 0) {
                ISSUE_AX(0, xrow); ISSUE_AX(1, (xrow + 256)); ISSUE_A0(2, (sprow + 2 * 256));
                CH(0, 16); CH(1, 8); CH(2, 0);
            } else if (w == 1) {
                ISSUE_A0(0, (sprow + 3 * 256)); ISSUE_A0(1, (sprow + 4 * 256)); ISSUE_A0(2, (sprow + 5 * 256));
                CH(0, 16); CH(1, 8); CH(2, 0);
            } else {
                const int ca = (w == 2) ? 6 : 8;
                ISSUE_A0(0, (sprow + ca * 256)); ISSUE_A0(1, (sprow + (ca + 1) * 256));
                const char* xb = (const char*)repP + (size_t)m * 512 + (size_t)cg2 * 16 + (size_t)r0s * 4096;
                ISSUE8P0(sregA, xb, xb + 4096, xb + 2*4096, xb + 3*4096,
                               xb + 4*4096, xb + 5*4096, xb + 6*4096, xb + 7*4096);
                ISSUE8P0(sregB, (xb + 8*4096), xb + 9*4096, xb + 10*4096, xb + 11*4096,
                               xb + 12*4096, xb + 13*4096, xb + 14*4096, xb + 15*4096);
                CH(0, 24); CH(1, 16);
                WAITV(0); SCHEDB;
                #pragma unroll
                for (int k = 0; k < 8; ++k) {
                    int b0 = r0s + k;
                    *(f16x8*)(xp_raw + (size_t)b0 * 512 + ((cg2 ^ (b0 & 7)) << 4)) = sregA[k];
                    int b1 = r0s + 8 + k;
                    *(f16x8*)(xp_raw + (size_t)b1 * 512 + ((cg2 ^ (b1 & 7)) << 4)) = sregB[k];
                }
            }

            f32x16 accS;
            #pragma unroll
            for (int r = 0; r < 16; ++r) accS[r] = acc0[r] + acc1[r];
            if (w > 0) {
                char* cb = smem + CMB_ACT + (w - 1) * 4096 + lane * 16;
                #pragma unroll
                for (int q = 0; q < 4; ++q) {
                    f32x4 v = { accS[q*4+0], accS[q*4+1], accS[q*4+2], accS[q*4+3] };
                    *(f32x4*)(cb + q * 1024) = v;
                }
            }
            LGKM0; BARRIER;
            // P1: lse over batch; wave0 folds combine tiles
            {
                int i = tid;
                int gq = i >> 3, r2 = (i & 7) * 2;
                float s = 0.f;
                #pragma unroll 8
                for (int b = 0; b < B_; ++b)
                    s += __expf((float)*(const f16*)(xp_raw + b * 512 + ((gq ^ (b & 7)) << 4) + r2));
                lse_lds[i] = __logf(s);
            }
            if (w == 0) {
                #pragma unroll
                for (int wv = 0; wv < 3; ++wv) {
                    const char* cb = smem + CMB_ACT + wv * 4096 + lane * 16;
                    #pragma unroll
                    for (int q = 0; q < 4; ++q) {
                        f32x4 v = *(const f32x4*)(cb + q * 1024);
                        accS[q*4+0] += v[0]; accS[q*4+1] += v[1];
                        accS[q*4+2] += v[2]; accS[q*4+3] += v[3];
                    }
                }
            }
            LGKM0; BARRIER;
            // P2: mean-surprisal partial dots
            {
                int b = tid >> 2, q = tid & 3;
                const float* xr = x + ((size_t)b * T_ + t) * I_ + q * 64;
                float s = 0.f;
                #pragma unroll
                for (int k = 0; k < 8; ++k) {
                    f16x8 xp8 = *(const f16x8*)(xp_raw + (size_t)b * 512 + ((((q << 3) + k) ^ (b & 7)) << 4));
                    f32x4 xa = *(const f32x4*)(xr + k * 8);
                    f32x4 xb2 = *(const f32x4*)(xr + k * 8 + 4);
                    #pragma unroll
                    for (int jj = 0; jj < 4; ++jj)
                        s += ((float)xp8[jj] - lse_lds[(q << 6) + (k << 3) + jj]) * xa[jj];
                    #pragma unroll
                    for (int jj = 0; jj < 4; ++jj)
                        s += ((float)xp8[jj + 4] - lse_lds[(q << 6) + (k << 3) + 4 + jj]) * xb2[jj];
                }
                part_lds[tid] = s;
            }
            LGKM0; BARRIER;
            // P3: gate
            if (tid < B_) {
                float s = part_lds[tid * 4] + part_lds[tid * 4 + 1] + part_lds[tid * 4 + 2] + part_lds[tid * 4 + 3];
                float mp = (s * (1.f / 256.f)) * per;
                gate_lds[tid] = 0.5f * (sinf((float)t * mp + shf) + 1.f);
                if ((a & 7) == 0) ps[((size_t)tid * T_ + t) * M_ + m] = mp;
            }
            LGKM0; BARRIER;
            // P4: wave0 blends + writes
            if (w == 0) {
                #pragma unroll
                for (int r = 0; r < 16; ++r) {
                    int rloc = (r & 3) + ((r >> 2) << 3) + (g << 2);
                    int row = row0 + rloc;
                    float gt = gate_lds[row];
                    float av = fast_tanh(accS[r] + bin);
                    float y = (1.f - gt) * av + gt * hreg[r];
                    hreg[r] = y;
                    st_coh_h(hnxt + (size_t)row * O_ + o0 + col, y);
                    ys[((size_t)row * T_ + t) * O_ + o0 + col] = y;
                    if (t == T_ - 1) hfin[(size_t)row * O_ + o0 + col] = y;
                }
            }
            WAITV(0);
            BARRIER;
            if (tid == 0) arriveB(bar, a, t);
        }
    }
}

extern "C" void kernel_launch(void* const* d_in, const int* in_sizes, int n_in,
                              void* d_out, int out_size, void* d_ws, size_t ws_size,
                              hipStream_t stream) {
    const float* x    = (const float*)d_in[0];
    const float* W_in = (const float*)d_in[1];
    const float* b_in = (const float*)d_in[2];
    const float* W_h  = (const float*)d_in[3];
    const float* W_ir = (const float*)d_in[4];
    const float* b_ir = (const float*)d_in[5];
    const float* W_hr = (const float*)d_in[6];
    const float* per  = (const float*)d_in[7];
    const float* shf  = (const float*)d_in[8];

    hipLaunchKernelGGL(init_kernel, dim3(256), dim3(256), 0, stream,
                       x, (char*)d_ws);
    hipLaunchKernelGGL(cwrnn_kernel, dim3(NB), dim3(THREADS), 0, stream,
                       x, W_in, b_in, W_h, W_ir, b_ir, W_hr, per, shf,
                       (float*)d_out, (char*)d_ws);
}

// Round 11
// 5483.918 us; speedup vs baseline: 1.1608x; 1.1608x over previous
//
#include <hip/hip_runtime.h>
#include <hip/hip_fp16.h>

typedef _Float16 f16;
typedef f16 f16x8 __attribute__((ext_vector_type(8)));
typedef f16 f16x4 __attribute__((ext_vector_type(4)));
typedef float f32x4 __attribute__((ext_vector_type(4)));
typedef float f32x16 __attribute__((ext_vector_type(16)));

#define B_ 64
#define T_ 512
#define I_ 256
#define O_ 1024
#define M_ 8
#define IM_ 2048
#define NRECB 128
#define NB 192
#define THREADS 256

// ws layout (bytes)
#define OFF_X16 16384ull
#define SZ_X16  16777216ull                     // [T][B][I] f16
#define OFF_XP4 (OFF_X16 + SZ_X16)              // 4 x [B][IM] f16 (quad buffer)
#define OFF_H2  (OFF_XP4 + 4ull * B_ * IM_ * 2) // 2 x [B][O] f16

// flag slot dword indices (16B apart): own-slot stores, gather-poll reads
// RECF[rh][i], i=0..63 ; ACTF[j], j = rh*32 + colg, 0..63
#define RECF_D(rh) (1024 + (rh) * 256)
#define ACTF_D     1536

// LDS layout
#define CMB_REC 147456
#define XPRAW   81920
#define CMB_ACT 114688
#define LSE_O   126976
#define PART_O  128000
#define GATE_O  129024
#define SMEM_SZ 159744

#define WAITV(N) asm volatile("s_waitcnt vmcnt(" #N ")" ::: "memory")
#define LGKM0    asm volatile("s_waitcnt lgkmcnt(0)" ::: "memory")
#define SCHEDB   __builtin_amdgcn_sched_barrier(0)
#define BARRIER  __builtin_amdgcn_s_barrier()

// 8 x 16B plain cached loads, 32B stride (read-only x16 input)
#define ISSUE_AX(BUF, P) asm volatile( \
    "global_load_dwordx4 %0, %8, off\n\t" \
    "global_load_dwordx4 %1, %8, off offset:32\n\t" \
    "global_load_dwordx4 %2, %8, off offset:64\n\t" \
    "global_load_dwordx4 %3, %8, off offset:96\n\t" \
    "global_load_dwordx4 %4, %8, off offset:128\n\t" \
    "global_load_dwordx4 %5, %8, off offset:160\n\t" \
    "global_load_dwordx4 %6, %8, off offset:192\n\t" \
    "global_load_dwordx4 %7, %8, off offset:224" \
    : "=&v"(abuf[BUF][0]), "=&v"(abuf[BUF][1]), "=&v"(abuf[BUF][2]), "=&v"(abuf[BUF][3]), \
      "=&v"(abuf[BUF][4]), "=&v"(abuf[BUF][5]), "=&v"(abuf[BUF][6]), "=&v"(abuf[BUF][7]) \
    : "v"(P) : "memory")

// 8 x 16B coherent (device-scope) loads, 32B stride (cross-XCD state)
#define ISSUE_AS(BUF, P) asm volatile( \
    "global_load_dwordx4 %0, %8, off sc0 sc1\n\t" \
    "global_load_dwordx4 %1, %8, off offset:32 sc0 sc1\n\t" \
    "global_load_dwordx4 %2, %8, off offset:64 sc0 sc1\n\t" \
    "global_load_dwordx4 %3, %8, off offset:96 sc0 sc1\n\t" \
    "global_load_dwordx4 %4, %8, off offset:128 sc0 sc1\n\t" \
    "global_load_dwordx4 %5, %8, off offset:160 sc0 sc1\n\t" \
    "global_load_dwordx4 %6, %8, off offset:192 sc0 sc1\n\t" \
    "global_load_dwordx4 %7, %8, off offset:224 sc0 sc1" \
    : "=&v"(abuf[BUF][0]), "=&v"(abuf[BUF][1]), "=&v"(abuf[BUF][2]), "=&v"(abuf[BUF][3]), \
      "=&v"(abuf[BUF][4]), "=&v"(abuf[BUF][5]), "=&v"(abuf[BUF][6]), "=&v"(abuf[BUF][7]) \
    : "v"(P) : "memory")

// 8 x 16B coherent loads from 8 independent addresses into named array
#define ISSUE8P(ARR, P0,P1,P2,P3,P4,P5,P6,P7) asm volatile( \
    "global_load_dwordx4 %0, %8, off sc0 sc1\n\t" \
    "global_load_dwordx4 %1, %9, off sc0 sc1\n\t" \
    "global_load_dwordx4 %2, %10, off sc0 sc1\n\t" \
    "global_load_dwordx4 %3, %11, off sc0 sc1\n\t" \
    "global_load_dwordx4 %4, %12, off sc0 sc1\n\t" \
    "global_load_dwordx4 %5, %13, off sc0 sc1\n\t" \
    "global_load_dwordx4 %6, %14, off sc0 sc1\n\t" \
    "global_load_dwordx4 %7, %15, off sc0 sc1" \
    : "=&v"((ARR)[0]), "=&v"((ARR)[1]), "=&v"((ARR)[2]), "=&v"((ARR)[3]), \
      "=&v"((ARR)[4]), "=&v"((ARR)[5]), "=&v"((ARR)[6]), "=&v"((ARR)[7]) \
    : "v"(P0), "v"(P1), "v"(P2), "v"(P3), "v"(P4), "v"(P5), "v"(P6), "v"(P7) \
    : "memory")

// one chunk: counted wait (+sched fence), 8 MFMA
#define CH(I, WN) do { \
    WAITV(WN); SCHEDB; \
    _Pragma("unroll") \
    for (int kb = 0; kb < 8; ++kb) { \
        f16x8 bf = *(const f16x8*)(smem + addrB[kb] + (I) * 256); \
        if (kb & 1) acc1 = __builtin_amdgcn_mfma_f32_32x32x16_f16(abuf[I][kb], bf, acc1, 0, 0, 0); \
        else        acc0 = __builtin_amdgcn_mfma_f32_32x32x16_f16(abuf[I][kb], bf, acc0, 0, 0, 0); \
    } \
} while (0)

__device__ __forceinline__ void st_coh_h(f16* p, float vf) {
    union { f16 h; short s; } u; u.h = (f16)vf;
    asm volatile("global_store_short %0, %1, off sc0 sc1" :: "v"(p), "v"((int)u.s) : "memory");
}

__device__ __forceinline__ float fast_tanh(float x) {
    float e = __expf(2.f * x);
    return 1.f - 2.f / (e + 1.f);
}

// uncached 4B flag read (L3-direct), per-lane
__device__ __forceinline__ int ld_flag(const unsigned* p) {
    int v;
    asm volatile("global_load_dword %0, %1, off sc0 sc1" : "=v"(v) : "v"(p) : "memory");
    WAITV(0);
    return v;
}
__device__ __forceinline__ void st_flag(unsigned* p, int v) {
    asm volatile("global_store_dword %0, %1, off sc0 sc1" :: "v"(p), "v"(v) : "memory");
}

// init: zero flag region, convert x [B,T,I] f32 -> x16 [T,B,I] f16, zero state buf0
__global__ void init_kernel(const float* __restrict__ x, char* __restrict__ ws) {
    const int gid = blockIdx.x * 256 + threadIdx.x;
    if (blockIdx.x == 0) {
        for (int i = threadIdx.x; i < 4096; i += 256) ((unsigned*)ws)[i] = 0u;
    }
    f16* x16 = (f16*)(ws + OFF_X16);
    const int NQ = T_ * B_ * (I_ / 4);
    for (int q = gid; q < NQ; q += 256 * 256) {
        int t = q >> 12;
        int rem = q & 4095;
        int b = rem >> 6;
        int k4 = rem & 63;
        f32x4 v = *(const f32x4*)(x + ((size_t)b * T_ + t) * I_ + k4 * 4);
        f16x4 h;
        h[0] = (f16)v[0]; h[1] = (f16)v[1]; h[2] = (f16)v[2]; h[3] = (f16)v[3];
        *(f16x4*)(x16 + ((size_t)t * B_ + b) * I_ + k4 * 4) = h;
    }
    f16x8 z = {0, 0, 0, 0, 0, 0, 0, 0};
    f16* xp0 = (f16*)(ws + OFF_XP4);
    for (int e = gid * 8; e < B_ * IM_; e += 256 * 256 * 8) *(f16x8*)(xp0 + e) = z;
    f16* h0 = (f16*)(ws + OFF_H2);
    for (int e = gid * 8; e < B_ * O_; e += 256 * 256 * 8) *(f16x8*)(h0 + e) = z;
}

__global__ __launch_bounds__(THREADS, 1) void cwrnn_kernel(
    const float* __restrict__ x, const float* __restrict__ W_in, const float* __restrict__ b_in,
    const float* __restrict__ W_h, const float* __restrict__ W_ir, const float* __restrict__ b_ir,
    const float* __restrict__ W_hr, const float* __restrict__ periods, const float* __restrict__ shifts,
    float* __restrict__ out, char* __restrict__ ws)
{
    __shared__ __align__(16) char smem[SMEM_SZ];

    unsigned* bar = (unsigned*)ws;
    const int blk = blockIdx.x, tid = threadIdx.x;
    const int lane = tid & 63, w = tid >> 6;
    const int col = lane & 31, g = lane >> 5;

    float* ys = out;
    float* hfin = out + (size_t)B_ * T_ * O_;
    float* ps = hfin + (size_t)B_ * O_;

    f16* const xpB = (f16*)(ws + OFF_XP4);
    f16* h2 = (f16*)(ws + OFF_H2);

    if (blk < NRECB) {
        // ========== REC: block = (col-group cg, row-half rh); 32 rows x 32 cols ==========
        const int cg = blk >> 1, rh = blk & 1;
        const int j0 = cg * 32;
        const int row0 = rh * 32;
        const int arow = row0 + col;
        {   // stage W2 = [W_ir | W_hr] rows j0..j0+31 into swizzled LDS (once)
            const int j = tid & 31;
            const float* ra = W_ir + (size_t)(j0 + j) * I_;
            const float* rb = W_hr + (size_t)(j0 + j) * IM_ - 256;
            for (int u = (tid >> 5); u < 288; u += 8) {
                int k0 = u * 8;
                const float* s = (k0 < 256) ? (ra + k0) : (rb + k0);
                f32x4 lo = *(const f32x4*)s;
                f32x4 hi = *(const f32x4*)(s + 4);
                f16x8 v;
                #pragma unroll
                for (int e = 0; e < 4; ++e) { v[e] = (f16)lo[e]; v[e + 4] = (f16)hi[e]; }
                *(f16x8*)(smem + j * 4608 + ((u ^ (j & 15)) << 4)) = v;
            }
        }
        const float bir = b_ir[j0 + col];
        LGKM0; BARRIER;

        const int c0k = (w == 0) ? 0 : (w == 1) ? 5 : (w == 2) ? 10 : 14;
        int addrB[8];
        #pragma unroll
        for (int kb = 0; kb < 8; ++kb)
            addrB[kb] = col * 4608 + ((((kb << 1) + g) ^ (col & 15)) << 4) + c0k * 256;

        const char* xrow0 = (const char*)(ws + OFF_X16) + (size_t)arow * 512 + g * 16;
        unsigned* myslot = bar + RECF_D(rh) + cg * 4;

        for (int t = 0; t < T_ - 1; ++t) {
            // ---- gather-poll: own-half REC flags >= t (w0); all ACT flags >= t-2 (w1) ----
            if (w == 0) {
                const unsigned* p = bar + RECF_D(rh) + lane * 4;
                while (__ballot(ld_flag(p) >= t) != ~0ull) __builtin_amdgcn_s_sleep(4);
            } else if (w == 1) {
                const unsigned* p = bar + ACTF_D + lane * 4;
                const int tgt = t - 2;
                while (__ballot(ld_flag(p) >= tgt) != ~0ull) __builtin_amdgcn_s_sleep(4);
            }
            BARRIER;
            const int bi = t & 3, bn = (t + 1) & 3;
            const f16* xpcur = xpB + (size_t)bi * B_ * IM_;
            f16* xpnxt = xpB + (size_t)bn * B_ * IM_;
            const char* sprow = (const char*)xpcur + (size_t)arow * 4096 + g * 16 - 512;
            const char* xrow = xrow0 + (size_t)t * 32768;

            f16x8 abuf[5][8];
            f32x16 acc0, acc1;
            #pragma unroll
            for (int r = 0; r < 16; ++r) { acc0[r] = 0.f; acc1[r] = 0.f; }

            if (w == 0) {
                ISSUE_AX(0, xrow); ISSUE_AX(1, (xrow + 256));
                ISSUE_AS(2, (sprow + 2 * 256)); ISSUE_AS(3, (sprow + 3 * 256)); ISSUE_AS(4, (sprow + 4 * 256));
                CH(0, 32); CH(1, 24); CH(2, 16); CH(3, 8); CH(4, 0);
            } else if (w == 1) {
                ISSUE_AS(0, (sprow + 5 * 256)); ISSUE_AS(1, (sprow + 6 * 256)); ISSUE_AS(2, (sprow + 7 * 256));
                ISSUE_AS(3, (sprow + 8 * 256)); ISSUE_AS(4, (sprow + 9 * 256));
                CH(0, 32); CH(1, 24); CH(2, 16); CH(3, 8); CH(4, 0);
            } else if (w == 2) {
                ISSUE_AS(0, (sprow + 10 * 256)); ISSUE_AS(1, (sprow + 11 * 256));
                ISSUE_AS(2, (sprow + 12 * 256)); ISSUE_AS(3, (sprow + 13 * 256));
                CH(0, 24); CH(1, 16); CH(2, 8); CH(3, 0);
            } else {
                ISSUE_AS(0, (sprow + 14 * 256)); ISSUE_AS(1, (sprow + 15 * 256));
                ISSUE_AS(2, (sprow + 16 * 256)); ISSUE_AS(3, (sprow + 17 * 256));
                CH(0, 24); CH(1, 16); CH(2, 8); CH(3, 0);
            }

            f32x16 accS;
            #pragma unroll
            for (int r = 0; r < 16; ++r) accS[r] = acc0[r] + acc1[r];
            if (w > 0) {
                char* cb = smem + CMB_REC + (w - 1) * 4096 + lane * 16;
                #pragma unroll
                for (int q = 0; q < 4; ++q) {
                    f32x4 v = { accS[q*4+0], accS[q*4+1], accS[q*4+2], accS[q*4+3] };
                    *(f32x4*)(cb + q * 1024) = v;
                }
            }
            LGKM0; BARRIER;
            if (w == 0) {
                #pragma unroll
                for (int wv = 0; wv < 3; ++wv) {
                    const char* cb = smem + CMB_REC + wv * 4096 + lane * 16;
                    #pragma unroll
                    for (int q = 0; q < 4; ++q) {
                        f32x4 v = *(const f32x4*)(cb + q * 1024);
                        accS[q*4+0] += v[0]; accS[q*4+1] += v[1];
                        accS[q*4+2] += v[2]; accS[q*4+3] += v[3];
                    }
                }
                #pragma unroll
                for (int r = 0; r < 16; ++r) {
                    int rloc = (r & 3) + ((r >> 2) << 3) + (g << 2);
                    st_coh_h(xpnxt + (size_t)(row0 + rloc) * IM_ + j0 + col, fast_tanh(accS[r] + bir));
                }
                WAITV(0);
                if (tid == 0) st_flag(myslot, t + 1);
            }
        }
    } else {
        // ========== ACT: block = (col-group colg, row-half rh); 32 rows x 32 cols ==========
        const int a = blk - NRECB;
        const int colg = a >> 1, rh = a & 1;
        const int m = colg >> 2;
        const int o0 = colg * 32;
        const int row0 = rh * 32;
        const int arow = row0 + col;
        {   // stage W1 = [W_in | W_h] rows o0..o0+31
            const int j = tid & 31;
            const float* ra = W_in + (size_t)(o0 + j) * I_;
            const float* rb = W_h + (size_t)(o0 + j) * O_ - 256;
            for (int u = (tid >> 5); u < 160; u += 8) {
                int k0 = u * 8;
                const float* s = (k0 < 256) ? (ra + k0) : (rb + k0);
                f32x4 lo = *(const f32x4*)s;
                f32x4 hi = *(const f32x4*)(s + 4);
                f16x8 v;
                #pragma unroll
                for (int e = 0; e < 4; ++e) { v[e] = (f16)lo[e]; v[e + 4] = (f16)hi[e]; }
                *(f16x8*)(smem + j * 2560 + ((u ^ (j & 15)) << 4)) = v;
            }
        }
        const float bin = b_in[o0 + col];
        const float per = periods[m], shf = shifts[m];
        LGKM0; BARRIER;

        const int c0k = (w == 0) ? 0 : (w == 1) ? 3 : (w == 2) ? 6 : 8;
        int addrB[8];
        #pragma unroll
        for (int kb = 0; kb < 8; ++kb)
            addrB[kb] = col * 2560 + ((((kb << 1) + g) ^ (col & 15)) << 4) + c0k * 256;

        char* xp_raw = smem + XPRAW;
        float* lse_lds = (float*)(smem + LSE_O);
        float* part_lds = (float*)(smem + PART_O);
        float* gate_lds = (float*)(smem + GATE_O);

        const char* xrow0 = (const char*)(ws + OFF_X16) + (size_t)arow * 512 + g * 16;
        unsigned* myslot = bar + ACTF_D + (rh * 32 + colg) * 4;
        float hreg[16];
        #pragma unroll
        for (int r = 0; r < 16; ++r) hreg[r] = 0.f;

        const int s_ = tid - 128;
        const int cg2 = s_ & 31;
        const int r0s = (s_ >> 5) << 4;

        for (int t = 0; t < T_; ++t) {
            // ---- gather-poll: RECF[0] >= t (w0); RECF[1] >= t (w1); own-half ACTF >= t (w2) ----
            if (w == 0) {
                const unsigned* p = bar + RECF_D(0) + lane * 4;
                while (__ballot(ld_flag(p) >= t) != ~0ull) __builtin_amdgcn_s_sleep(4);
            } else if (w == 1) {
                const unsigned* p = bar + RECF_D(1) + lane * 4;
                while (__ballot(ld_flag(p) >= t) != ~0ull) __builtin_amdgcn_s_sleep(4);
            } else if (w == 2) {
                const unsigned* p = bar + ACTF_D + (rh * 32 + (lane & 31)) * 4;
                while (__ballot((lane < 32) ? (ld_flag(p) >= t) : 1) != ~0ull) __builtin_amdgcn_s_sleep(4);
            }
            BARRIER;
            const int bi = t & 3;
            const f16* xpcur = xpB + (size_t)bi * B_ * IM_;
            const f16* hcur = h2 + (size_t)(t & 1) * B_ * O_;
            f16* hnxt = h2 + (size_t)((t + 1) & 1) * B_ * O_;

            const char* sprow = (const char*)hcur + (size_t)arow * 2048 + g * 16 - 512;
            const char* xrow = xrow0 + (size_t)t * 32768;
            f16x8 abuf[3][8];
            f16x8 sregA[8], sregB[8];
            f32x16 acc0, acc1;
            #pragma unroll
            for (int r = 0; r < 16; ++r) { acc0[r] = 0.f; acc1[r] = 0.f; }

            if (w == 0) {
                ISSUE_AX(0, xrow); ISSUE_AX(1, (xrow + 256)); ISSUE_AS(2, (sprow + 2 * 256));
                CH(0, 16); CH(1, 8); CH(2, 0);
            } else if (w == 1) {
                ISSUE_AS(0, (sprow + 3 * 256)); ISSUE_AS(1, (sprow + 4 * 256)); ISSUE_AS(2, (sprow + 5 * 256));
                CH(0, 16); CH(1, 8); CH(2, 0);
            } else {
                const int ca = (w == 2) ? 6 : 8;
                ISSUE_AS(0, (sprow + ca * 256)); ISSUE_AS(1, (sprow + (ca + 1) * 256));
                const char* xb = (const char*)xpcur + (size_t)m * 512 + (size_t)cg2 * 16 + (size_t)r0s * 4096;
                ISSUE8P(sregA, xb, xb + 4096, xb + 2*4096, xb + 3*4096,
                               xb + 4*4096, xb + 5*4096, xb + 6*4096, xb + 7*4096);
                ISSUE8P(sregB, (xb + 8*4096), xb + 9*4096, xb + 10*4096, xb + 11*4096,
                               xb + 12*4096, xb + 13*4096, xb + 14*4096, xb + 15*4096);
                CH(0, 24); CH(1, 16);
                WAITV(0); SCHEDB;
                #pragma unroll
                for (int k = 0; k < 8; ++k) {
                    int b0 = r0s + k;
                    *(f16x8*)(xp_raw + (size_t)b0 * 512 + ((cg2 ^ (b0 & 7)) << 4)) = sregA[k];
                    int b1 = r0s + 8 + k;
                    *(f16x8*)(xp_raw + (size_t)b1 * 512 + ((cg2 ^ (b1 & 7)) << 4)) = sregB[k];
                }
            }

            f32x16 accS;
            #pragma unroll
            for (int r = 0; r < 16; ++r) accS[r] = acc0[r] + acc1[r];
            if (w > 0) {
                char* cb = smem + CMB_ACT + (w - 1) * 4096 + lane * 16;
                #pragma unroll
                for (int q = 0; q < 4; ++q) {
                    f32x4 v = { accS[q*4+0], accS[q*4+1], accS[q*4+2], accS[q*4+3] };
                    *(f32x4*)(cb + q * 1024) = v;
                }
            }
            LGKM0; BARRIER;
            // P1: lse over batch; wave0 folds combine tiles
            {
                int i = tid;
                int gq = i >> 3, r2 = (i & 7) * 2;
                float s = 0.f;
                #pragma unroll 8
                for (int b = 0; b < B_; ++b)
                    s += __expf((float)*(const f16*)(xp_raw + b * 512 + ((gq ^ (b & 7)) << 4) + r2));
                lse_lds[i] = __logf(s);
            }
            if (w == 0) {
                #pragma unroll
                for (int wv = 0; wv < 3; ++wv) {
                    const char* cb = smem + CMB_ACT + wv * 4096 + lane * 16;
                    #pragma unroll
                    for (int q = 0; q < 4; ++q) {
                        f32x4 v = *(const f32x4*)(cb + q * 1024);
                        accS[q*4+0] += v[0]; accS[q*4+1] += v[1];
                        accS[q*4+2] += v[2]; accS[q*4+3] += v[3];
                    }
                }
            }
            LGKM0; BARRIER;
            // P2: mean-surprisal partial dots
            {
                int b = tid >> 2, q = tid & 3;
                const float* xr = x + ((size_t)b * T_ + t) * I_ + q * 64;
                float s = 0.f;
                #pragma unroll
                for (int k = 0; k < 8; ++k) {
                    f16x8 xp8 = *(const f16x8*)(xp_raw + (size_t)b * 512 + ((((q << 3) + k) ^ (b & 7)) << 4));
                    f32x4 xa = *(const f32x4*)(xr + k * 8);
                    f32x4 xb2 = *(const f32x4*)(xr + k * 8 + 4);
                    #pragma unroll
                    for (int jj = 0; jj < 4; ++jj)
                        s += ((float)xp8[jj] - lse_lds[(q << 6) + (k << 3) + jj]) * xa[jj];
                    #pragma unroll
                    for (int jj = 0; jj < 4; ++jj)
                        s += ((float)xp8[jj + 4] - lse_lds[(q << 6) + (k << 3) + 4 + jj]) * xb2[jj];
                }
                part_lds[tid] = s;
            }
            LGKM0; BARRIER;
            // P3: gate
            if (tid < B_) {
                float s = part_lds[tid * 4] + part_lds[tid * 4 + 1] + part_lds[tid * 4 + 2] + part_lds[tid * 4 + 3];
                float mp = (s * (1.f / 256.f)) * per;
                gate_lds[tid] = 0.5f * (sinf((float)t * mp + shf) + 1.f);
                if ((a & 7) == 0) ps[((size_t)tid * T_ + t) * M_ + m] = mp;
            }
            LGKM0; BARRIER;
            // P4: wave0 blends + writes, posts own flag
            if (w == 0) {
                #pragma unroll
                for (int r = 0; r < 16; ++r) {
                    int rloc = (r & 3) + ((r >> 2) << 3) + (g << 2);
                    int row = row0 + rloc;
                    float gt = gate_lds[row];
                    float av = fast_tanh(accS[r] + bin);
                    float y = (1.f - gt) * av + gt * hreg[r];
                    hreg[r] = y;
                    st_coh_h(hnxt + (size_t)row * O_ + o0 + col, y);
                    ys[((size_t)row * T_ + t) * O_ + o0 + col] = y;
                    if (t == T_ - 1) hfin[(size_t)row * O_ + o0 + col] = y;
                }
                WAITV(0);
                if (tid == 0) st_flag(myslot, t + 1);
            }
        }
    }
}

extern "C" void kernel_launch(void* const* d_in, const int* in_sizes, int n_in,
                              void* d_out, int out_size, void* d_ws, size_t ws_size,
                              hipStream_t stream) {
    const float* x    = (const float*)d_in[0];
    const float* W_in = (const float*)d_in[1];
    const float* b_in = (const float*)d_in[2];
    const float* W_h  = (const float*)d_in[3];
    const float* W_ir = (const float*)d_in[4];
    const float* b_ir = (const float*)d_in[5];
    const float* W_hr = (const float*)d_in[6];
    const float* per  = (const float*)d_in[7];
    const float* shf  = (const float*)d_in[8];

    hipLaunchKernelGGL(init_kernel, dim3(256), dim3(256), 0, stream,
                       x, (char*)d_ws);
    hipLaunchKernelGGL(cwrnn_kernel, dim3(NB), dim3(THREADS), 0, stream,
                       x, W_in, b_in, W_h, W_ir, b_ir, W_hr, per, shf,
                       (float*)d_out, (char*)d_ws);
}

// Round 12
// 5427.182 us; speedup vs baseline: 1.1729x; 1.0105x over previous
//
#include <hip/hip_runtime.h>
#include <hip/hip_fp16.h>

typedef _Float16 f16;
typedef f16 f16x8 __attribute__((ext_vector_type(8)));
typedef f16 f16x4 __attribute__((ext_vector_type(4)));
typedef float f32x4 __attribute__((ext_vector_type(4)));
typedef float f32x16 __attribute__((ext_vector_type(16)));

#define B_ 64
#define T_ 512
#define I_ 256
#define O_ 1024
#define M_ 8
#define IM_ 2048
#define NRECB 128
#define NB 192
#define THREADS 256

// ws layout (bytes)
#define OFF_X16 16384ull
#define SZ_X16  16777216ull                       // [T][B][I] f16
#define OFF_XP4 (OFF_X16 + SZ_X16)                // 4 x [B][IM] f16
#define OFF_H4  (OFF_XP4 + 4ull * B_ * IM_ * 2)   // 4 x [B][O] f16

// flag dword indices (16B-separated slots)
#define RECF_D(rh) (1024 + (rh) * 256)
#define ACTF_D     1536
#define XCDF_D(x)  (2048 + (x) * 16)
#define NRC_D(x)   (2560 + (x) * 16)
#define NAC_D(x)   (2688 + (x) * 16)
#define REGC_D     2816

// LDS layout
#define CMB_REC 147456
#define XPRAW   81920
#define CMB_ACT 114688
#define LSE_O   126976
#define PART_O  128000
#define GATE_O  129024
#define META_O  159744
#define SMEM_SZ 159808

#define WAITV(N) asm volatile("s_waitcnt vmcnt(" #N ")" ::: "memory")
#define LGKM0    asm volatile("s_waitcnt lgkmcnt(0)" ::: "memory")
#define SCHEDB   __builtin_amdgcn_sched_barrier(0)
#define BARRIER  __builtin_amdgcn_s_barrier()
#define ACQ_FENCE __builtin_amdgcn_fence(__ATOMIC_ACQUIRE, "agent")

// 8 x 16B plain cached loads, 32B stride (read-only x16 input)
#define ISSUE_AX(BUF, P) asm volatile( \
    "global_load_dwordx4 %0, %8, off\n\t" \
    "global_load_dwordx4 %1, %8, off offset:32\n\t" \
    "global_load_dwordx4 %2, %8, off offset:64\n\t" \
    "global_load_dwordx4 %3, %8, off offset:96\n\t" \
    "global_load_dwordx4 %4, %8, off offset:128\n\t" \
    "global_load_dwordx4 %5, %8, off offset:160\n\t" \
    "global_load_dwordx4 %6, %8, off offset:192\n\t" \
    "global_load_dwordx4 %7, %8, off offset:224" \
    : "=&v"(abuf[BUF][0]), "=&v"(abuf[BUF][1]), "=&v"(abuf[BUF][2]), "=&v"(abuf[BUF][3]), \
      "=&v"(abuf[BUF][4]), "=&v"(abuf[BUF][5]), "=&v"(abuf[BUF][6]), "=&v"(abuf[BUF][7]) \
    : "v"(P) : "memory")

// 8 x 16B sc0 loads (L1-bypass, XCD-L2-allocating): state reads post-inv
#define ISSUE_A0(BUF, P) asm volatile( \
    "global_load_dwordx4 %0, %8, off sc0\n\t" \
    "global_load_dwordx4 %1, %8, off offset:32 sc0\n\t" \
    "global_load_dwordx4 %2, %8, off offset:64 sc0\n\t" \
    "global_load_dwordx4 %3, %8, off offset:96 sc0\n\t" \
    "global_load_dwordx4 %4, %8, off offset:128 sc0\n\t" \
    "global_load_dwordx4 %5, %8, off offset:160 sc0\n\t" \
    "global_load_dwordx4 %6, %8, off offset:192 sc0\n\t" \
    "global_load_dwordx4 %7, %8, off offset:224 sc0" \
    : "=&v"(abuf[BUF][0]), "=&v"(abuf[BUF][1]), "=&v"(abuf[BUF][2]), "=&v"(abuf[BUF][3]), \
      "=&v"(abuf[BUF][4]), "=&v"(abuf[BUF][5]), "=&v"(abuf[BUF][6]), "=&v"(abuf[BUF][7]) \
    : "v"(P) : "memory")

// 8 x 16B sc0 loads from 8 independent addresses
#define ISSUE8P0(ARR, P0,P1,P2,P3,P4,P5,P6,P7) asm volatile( \
    "global_load_dwordx4 %0, %8, off sc0\n\t" \
    "global_load_dwordx4 %1, %9, off sc0\n\t" \
    "global_load_dwordx4 %2, %10, off sc0\n\t" \
    "global_load_dwordx4 %3, %11, off sc0\n\t" \
    "global_load_dwordx4 %4, %12, off sc0\n\t" \
    "global_load_dwordx4 %5, %13, off sc0\n\t" \
    "global_load_dwordx4 %6, %14, off sc0\n\t" \
    "global_load_dwordx4 %7, %15, off sc0" \
    : "=&v"((ARR)[0]), "=&v"((ARR)[1]), "=&v"((ARR)[2]), "=&v"((ARR)[3]), \
      "=&v"((ARR)[4]), "=&v"((ARR)[5]), "=&v"((ARR)[6]), "=&v"((ARR)[7]) \
    : "v"(P0), "v"(P1), "v"(P2), "v"(P3), "v"(P4), "v"(P5), "v"(P6), "v"(P7) \
    : "memory")

// one chunk: counted wait (+sched fence), 8 MFMA
#define CH(I, WN) do { \
    WAITV(WN); SCHEDB; \
    _Pragma("unroll") \
    for (int kb = 0; kb < 8; ++kb) { \
        f16x8 bf = *(const f16x8*)(smem + addrB[kb] + (I) * 256); \
        if (kb & 1) acc1 = __builtin_amdgcn_mfma_f32_32x32x16_f16(abuf[I][kb], bf, acc1, 0, 0, 0); \
        else        acc0 = __builtin_amdgcn_mfma_f32_32x32x16_f16(abuf[I][kb], bf, acc0, 0, 0, 0); \
    } \
} while (0)

__device__ __forceinline__ void st_coh_h(f16* p, float vf) {
    union { f16 h; short s; } u; u.h = (f16)vf;
    asm volatile("global_store_short %0, %1, off sc0 sc1" :: "v"(p), "v"((int)u.s) : "memory");
}

__device__ __forceinline__ float fast_tanh(float x) {
    float e = __expf(2.f * x);
    return 1.f - 2.f / (e + 1.f);
}

// raw L3-direct 4B flag read/write (no cache maintenance side effects)
__device__ __forceinline__ int ld_flag(const unsigned* p) {
    int v;
    asm volatile("global_load_dword %0, %1, off sc0 sc1" : "=v"(v) : "v"(p) : "memory");
    WAITV(0);
    return v;
}
__device__ __forceinline__ void st_flag(unsigned* p, int v) {
    asm volatile("global_store_dword %0, %1, off sc0 sc1" :: "v"(p), "v"(v) : "memory");
}
__device__ __forceinline__ unsigned ld_rlx(unsigned* p) {
    return __hip_atomic_load(p, __ATOMIC_RELAXED, __HIP_MEMORY_SCOPE_AGENT);
}
__device__ __forceinline__ unsigned rmw_add(unsigned* p) {
    return __hip_atomic_fetch_add(p, 1u, __ATOMIC_RELAXED, __HIP_MEMORY_SCOPE_AGENT);
}

// init: zero flag region, convert x [B,T,I] f32 -> x16 [T,B,I] f16, zero state buf0
__global__ void init_kernel(const float* __restrict__ x, char* __restrict__ ws) {
    const int gid = blockIdx.x * 256 + threadIdx.x;
    if (blockIdx.x == 0) {
        for (int i = threadIdx.x; i < 4096; i += 256) ((unsigned*)ws)[i] = 0u;
    }
    f16* x16 = (f16*)(ws + OFF_X16);
    const int NQ = T_ * B_ * (I_ / 4);
    for (int q = gid; q < NQ; q += 256 * 256) {
        int t = q >> 12;
        int rem = q & 4095;
        int b = rem >> 6;
        int k4 = rem & 63;
        f32x4 v = *(const f32x4*)(x + ((size_t)b * T_ + t) * I_ + k4 * 4);
        f16x4 h;
        h[0] = (f16)v[0]; h[1] = (f16)v[1]; h[2] = (f16)v[2]; h[3] = (f16)v[3];
        *(f16x4*)(x16 + ((size_t)t * B_ + b) * I_ + k4 * 4) = h;
    }
    f16x8 z = {0, 0, 0, 0, 0, 0, 0, 0};
    f16* xp0 = (f16*)(ws + OFF_XP4);
    for (int e = gid * 8; e < B_ * IM_; e += 256 * 256 * 8) *(f16x8*)(xp0 + e) = z;
    f16* h0 = (f16*)(ws + OFF_H4);
    for (int e = gid * 8; e < B_ * O_; e += 256 * 256 * 8) *(f16x8*)(h0 + e) = z;
}

__global__ __launch_bounds__(THREADS, 1) void cwrnn_kernel(
    const float* __restrict__ x, const float* __restrict__ W_in, const float* __restrict__ b_in,
    const float* __restrict__ W_h, const float* __restrict__ b_ir_dummy_Wh_, const float* __restrict__ W_ir_,
    const float* __restrict__ W_hr_, const float* __restrict__ periods, const float* __restrict__ shifts,
    float* __restrict__ out, char* __restrict__ ws);

__global__ __launch_bounds__(THREADS, 1) void cwrnn_main(
    const float* __restrict__ x, const float* __restrict__ W_in, const float* __restrict__ b_in,
    const float* __restrict__ W_h, const float* __restrict__ W_ir, const float* __restrict__ b_ir,
    const float* __restrict__ W_hr, const float* __restrict__ periods, const float* __restrict__ shifts,
    float* __restrict__ out, char* __restrict__ ws)
{
    __shared__ __align__(16) char smem[SMEM_SZ];

    unsigned* bar = (unsigned*)ws;
    const int blk = blockIdx.x, tid = threadIdx.x;
    const int lane = tid & 63, w = tid >> 6;
    const int col = lane & 31, g = lane >> 5;

    float* ys = out;
    float* hfin = out + (size_t)B_ * T_ * O_;
    float* ps = hfin + (size_t)B_ * O_;

    f16* const xpB = (f16*)(ws + OFF_XP4);
    f16* h4 = (f16*)(ws + OFF_H4);
    const bool isREC = (blk < NRECB);

    // ---- registration: learn XCD, rank; elect per-XCD leader (prefer REC) ----
    int* meta = (int*)(smem + META_O);
    if (tid == 0) {
        unsigned xcdv;
        asm volatile("s_getreg_b32 %0, hwreg(HW_REG_XCC_ID)" : "=s"(xcdv));
        xcdv &= 7u;
        unsigned rnk = rmw_add(&bar[isREC ? NRC_D(xcdv) : NAC_D(xcdv)]);
        WAITV(0);
        rmw_add(&bar[REGC_D]);
        while (ld_rlx(&bar[REGC_D]) < (unsigned)NB) __builtin_amdgcn_s_sleep(8);
        meta[0] = (int)xcdv;
        meta[1] = (int)rnk;
        meta[2] = (int)ld_rlx(&bar[NRC_D(xcdv)]);
    }
    LGKM0; BARRIER;
    const int xcd_ = meta[0], rank = meta[1], nRx = meta[2];
    const bool leader = isREC ? (rank == 0) : (rank == 0 && nRx == 0);
    unsigned* xcdfp = bar + XCDF_D(xcd_);

    if (isREC) {
        // ========== REC: block = (col-group cg, row-half rh); 32 rows x 32 cols ==========
        const int cg = blk >> 1, rh = blk & 1;
        const int j0 = cg * 32;
        const int row0 = rh * 32;
        const int arow = row0 + col;
        {   // stage W2 = [W_ir | W_hr] rows j0..j0+31 into swizzled LDS (once)
            const int j = tid & 31;
            const float* ra = W_ir + (size_t)(j0 + j) * I_;
            const float* rb = W_hr + (size_t)(j0 + j) * IM_ - 256;
            for (int u = (tid >> 5); u < 288; u += 8) {
                int k0 = u * 8;
                const float* s = (k0 < 256) ? (ra + k0) : (rb + k0);
                f32x4 lo = *(const f32x4*)s;
                f32x4 hi = *(const f32x4*)(s + 4);
                f16x8 v;
                #pragma unroll
                for (int e = 0; e < 4; ++e) { v[e] = (f16)lo[e]; v[e + 4] = (f16)hi[e]; }
                *(f16x8*)(smem + j * 4608 + ((u ^ (j & 15)) << 4)) = v;
            }
        }
        const float bir = b_ir[j0 + col];
        LGKM0; BARRIER;

        const int c0k = (w == 0) ? 0 : (w == 1) ? 5 : (w == 2) ? 10 : 14;
        int addrB[8];
        #pragma unroll
        for (int kb = 0; kb < 8; ++kb)
            addrB[kb] = col * 4608 + ((((kb << 1) + g) ^ (col & 15)) << 4) + c0k * 256;

        const char* xrow0 = (const char*)(ws + OFF_X16) + (size_t)arow * 512 + g * 16;
        unsigned* myslot = bar + RECF_D(rh) + cg * 4;

        for (int t = 0; t < T_ - 1; ++t) {
            // ---- poll + per-XCD L2 invalidate handshake ----
            if (leader) {
                if (w == 0) {
                    const unsigned* p = bar + RECF_D(0) + lane * 4;
                    while (__ballot(ld_flag(p) >= t) != ~0ull) __builtin_amdgcn_s_sleep(2);
                } else if (w == 1) {
                    const unsigned* p = bar + RECF_D(1) + lane * 4;
                    while (__ballot(ld_flag(p) >= t) != ~0ull) __builtin_amdgcn_s_sleep(2);
                } else if (w == 2) {
                    const unsigned* p = bar + ACTF_D + lane * 4;
                    const int tgt = t - 2;
                    while (__ballot(ld_flag(p) >= tgt) != ~0ull) __builtin_amdgcn_s_sleep(2);
                }
                BARRIER;
                if (tid == 0) { ACQ_FENCE; WAITV(0); st_flag(xcdfp, t + 1); }
                BARRIER;
            } else {
                if (w == 0) {
                    const unsigned* p = xcdfp;
                    while (__ballot(ld_flag(p) >= t + 1) != ~0ull) __builtin_amdgcn_s_sleep(2);
                } else if (w == 1) {
                    const unsigned* p = bar + ACTF_D + lane * 4;
                    const int tgt = t - 2;
                    while (__ballot(ld_flag(p) >= tgt) != ~0ull) __builtin_amdgcn_s_sleep(2);
                }
                BARRIER;
            }
            const int bi = t & 3, bn = (t + 1) & 3;
            const f16* xpcur = xpB + (size_t)bi * B_ * IM_;
            f16* xpnxt = xpB + (size_t)bn * B_ * IM_;
            const char* sprow = (const char*)xpcur + (size_t)arow * 4096 + g * 16 - 512;
            const char* xrow = xrow0 + (size_t)t * 32768;

            f16x8 abuf[5][8];
            f32x16 acc0, acc1;
            #pragma unroll
            for (int r = 0; r < 16; ++r) { acc0[r] = 0.f; acc1[r] = 0.f; }

            if (w == 0) {
                ISSUE_AX(0, xrow); ISSUE_AX(1, (xrow + 256));
                ISSUE_A0(2, (sprow + 2 * 256)); ISSUE_A0(3, (sprow + 3 * 256)); ISSUE_A0(4, (sprow + 4 * 256));
                CH(0, 32); CH(1, 24); CH(2, 16); CH(3, 8); CH(4, 0);
            } else if (w == 1) {
                ISSUE_A0(0, (sprow + 5 * 256)); ISSUE_A0(1, (sprow + 6 * 256)); ISSUE_A0(2, (sprow + 7 * 256));
                ISSUE_A0(3, (sprow + 8 * 256)); ISSUE_A0(4, (sprow + 9 * 256));
                CH(0, 32); CH(1, 24); CH(2, 16); CH(3, 8); CH(4, 0);
            } else if (w == 2) {
                ISSUE_A0(0, (sprow + 10 * 256)); ISSUE_A0(1, (sprow + 11 * 256));
                ISSUE_A0(2, (sprow + 12 * 256)); ISSUE_A0(3, (sprow + 13 * 256));
                CH(0, 24); CH(1, 16); CH(2, 8); CH(3, 0);
            } else {
                ISSUE_A0(0, (sprow + 14 * 256)); ISSUE_A0(1, (sprow + 15 * 256));
                ISSUE_A0(2, (sprow + 16 * 256)); ISSUE_A0(3, (sprow + 17 * 256));
                CH(0, 24); CH(1, 16); CH(2, 8); CH(3, 0);
            }

            f32x16 accS;
            #pragma unroll
            for (int r = 0; r < 16; ++r) accS[r] = acc0[r] + acc1[r];
            if (w > 0) {
                char* cb = smem + CMB_REC + (w - 1) * 4096 + lane * 16;
                #pragma unroll
                for (int q = 0; q < 4; ++q) {
                    f32x4 v = { accS[q*4+0], accS[q*4+1], accS[q*4+2], accS[q*4+3] };
                    *(f32x4*)(cb + q * 1024) = v;
                }
            }
            LGKM0; BARRIER;
            if (w == 0) {
                #pragma unroll
                for (int wv = 0; wv < 3; ++wv) {
                    const char* cb = smem + CMB_REC + wv * 4096 + lane * 16;
                    #pragma unroll
                    for (int q = 0; q < 4; ++q) {
                        f32x4 v = *(const f32x4*)(cb + q * 1024);
                        accS[q*4+0] += v[0]; accS[q*4+1] += v[1];
                        accS[q*4+2] += v[2]; accS[q*4+3] += v[3];
                    }
                }
                #pragma unroll
                for (int r = 0; r < 16; ++r) {
                    int rloc = (r & 3) + ((r >> 2) << 3) + (g << 2);
                    st_coh_h(xpnxt + (size_t)(row0 + rloc) * IM_ + j0 + col, fast_tanh(accS[r] + bir));
                }
                WAITV(0);
                if (tid == 0) st_flag(myslot, t + 1);
            }
        }
        // leader epilogue: one more inv+post so ACT can run its final epoch T-1
        if (leader) {
            const int tt = T_ - 1;
            if (w == 0) {
                const unsigned* p = bar + RECF_D(0) + lane * 4;
                while (__ballot(ld_flag(p) >= tt) != ~0ull) __builtin_amdgcn_s_sleep(2);
            } else if (w == 1) {
                const unsigned* p = bar + RECF_D(1) + lane * 4;
                while (__ballot(ld_flag(p) >= tt) != ~0ull) __builtin_amdgcn_s_sleep(2);
            }
            BARRIER;
            if (tid == 0) { ACQ_FENCE; WAITV(0); st_flag(xcdfp, tt + 1); }
        }
    } else {
        // ========== ACT: block = (col-group colg, row-half rh); 32 rows x 32 cols ==========
        const int a = blk - NRECB;
        const int colg = a >> 1, rh = a & 1;
        const int m = colg >> 2;
        const int o0 = colg * 32;
        const int row0 = rh * 32;
        const int arow = row0 + col;
        {   // stage W1 = [W_in | W_h] rows o0..o0+31
            const int j = tid & 31;
            const float* ra = W_in + (size_t)(o0 + j) * I_;
            const float* rb = W_h + (size_t)(o0 + j) * O_ - 256;
            for (int u = (tid >> 5); u < 160; u += 8) {
                int k0 = u * 8;
                const float* s = (k0 < 256) ? (ra + k0) : (rb + k0);
                f32x4 lo = *(const f32x4*)s;
                f32x4 hi = *(const f32x4*)(s + 4);
                f16x8 v;
                #pragma unroll
                for (int e = 0; e < 4; ++e) { v[e] = (f16)lo[e]; v[e + 4] = (f16)hi[e]; }
                *(f16x8*)(smem + j * 2560 + ((u ^ (j & 15)) << 4)) = v;
            }
        }
        const float bin = b_in[o0 + col];
        const float per = periods[m], shf = shifts[m];
        LGKM0; BARRIER;

        const int c0k = (w == 0) ? 0 : (w == 1) ? 3 : (w == 2) ? 6 : 8;
        int addrB[8];
        #pragma unroll
        for (int kb = 0; kb < 8; ++kb)
            addrB[kb] = col * 2560 + ((((kb << 1) + g) ^ (col & 15)) << 4) + c0k * 256;

        char* xp_raw = smem + XPRAW;
        float* lse_lds = (float*)(smem + LSE_O);
        float* part_lds = (float*)(smem + PART_O);
        float* gate_lds = (float*)(smem + GATE_O);

        const char* xrow0 = (const char*)(ws + OFF_X16) + (size_t)arow * 512 + g * 16;
        unsigned* myslot = bar + ACTF_D + (rh * 32 + colg) * 4;
        float hreg[16];
        #pragma unroll
        for (int r = 0; r < 16; ++r) hreg[r] = 0.f;

        const int s_ = tid - 128;
        const int cg2 = s_ & 31;
        const int r0s = (s_ >> 5) << 4;

        for (int t = 0; t < T_; ++t) {
            if (leader) {
                if (w == 0) {
                    const unsigned* p = bar + RECF_D(0) + lane * 4;
                    while (__ballot(ld_flag(p) >= t) != ~0ull) __builtin_amdgcn_s_sleep(2);
                } else if (w == 1) {
                    const unsigned* p = bar + RECF_D(1) + lane * 4;
                    while (__ballot(ld_flag(p) >= t) != ~0ull) __builtin_amdgcn_s_sleep(2);
                } else if (w == 2) {
                    const unsigned* p = bar + ACTF_D + (rh * 32 + (lane & 31)) * 4;
                    while (__ballot((lane < 32) ? (ld_flag(p) >= t) : 1) != ~0ull) __builtin_amdgcn_s_sleep(2);
                }
                BARRIER;
                if (tid == 0) { ACQ_FENCE; WAITV(0); st_flag(xcdfp, t + 1); }
                BARRIER;
            } else {
                if (w == 0) {
                    const unsigned* p = xcdfp;
                    while (__ballot(ld_flag(p) >= t + 1) != ~0ull) __builtin_amdgcn_s_sleep(2);
                } else if (w == 1) {
                    const unsigned* p = bar + ACTF_D + (rh * 32 + (lane & 31)) * 4;
                    while (__ballot((lane < 32) ? (ld_flag(p) >= t) : 1) != ~0ull) __builtin_amdgcn_s_sleep(2);
                }
                BARRIER;
            }
            const int bi = t & 3;
            const f16* xpcur = xpB + (size_t)bi * B_ * IM_;
            const f16* hcur = h4 + (size_t)(t & 3) * B_ * O_;
            f16* hnxt = h4 + (size_t)((t + 1) & 3) * B_ * O_;

            const char* sprow = (const char*)hcur + (size_t)arow * 2048 + g * 16 - 512;
            const char* xrow = xrow0 + (size_t)t * 32768;
            f16x8 abuf[3][8];
            f16x8 sregA[8], sregB[8];
            f32x16 acc0, acc1;
            #pragma unroll
            for (int r = 0; r < 16; ++r) { acc0[r] = 0.f; acc1[r] = 0.f; }

            if (w == 0) {
                ISSUE_AX(0, xrow); ISSUE_AX(1, (xrow + 256)); ISSUE_A0(2, (sprow + 2 * 256));
                CH(0, 16); CH(1, 8); CH(2, 0);
            } else if (w == 1) {
                ISSUE_A0(0, (sprow + 3 * 256)); ISSUE_A0(1, (sprow + 4 * 256)); ISSUE_A0(2, (sprow + 5 * 256));
                CH(0, 16); CH(1, 8); CH(2, 0);
            } else {
                const int ca = (w == 2) ? 6 : 8;
                ISSUE_A0(0, (sprow + ca * 256)); ISSUE_A0(1, (sprow + (ca + 1) * 256));
                const char* xb = (const char*)xpcur + (size_t)m * 512 + (size_t)cg2 * 16 + (size_t)r0s * 4096;
                ISSUE8P0(sregA, xb, xb + 4096, xb + 2*4096, xb + 3*4096,
                               xb + 4*4096, xb + 5*4096, xb + 6*4096, xb + 7*4096);
                ISSUE8P0(sregB, (xb + 8*4096), xb + 9*4096, xb + 10*4096, xb + 11*4096,
                               xb + 12*4096, xb + 13*4096, xb + 14*4096, xb + 15*4096);
                CH(0, 24); CH(1, 16);
                WAITV(0); SCHEDB;
                #pragma unroll
                for (int k = 0; k < 8; ++k) {
                    int b0 = r0s + k;
                    *(f16x8*)(xp_raw + (size_t)b0 * 512 + ((cg2 ^ (b0 & 7)) << 4)) = sregA[k];
                    int b1 = r0s + 8 + k;
                    *(f16x8*)(xp_raw + (size_t)b1 * 512 + ((cg2 ^ (b1 & 7)) << 4)) = sregB[k];
                }
            }

            f32x16 accS;
            #pragma unroll
            for (int r = 0; r < 16; ++r) accS[r] = acc0[r] + acc1[r];
            if (w > 0) {
                char* cb = smem + CMB_ACT + (w - 1) * 4096 + lane * 16;
                #pragma unroll
                for (int q = 0; q < 4; ++q) {
                    f32x4 v = { accS[q*4+0], accS[q*4+1], accS[q*4+2], accS[q*4+3] };
                    *(f32x4*)(cb + q * 1024) = v;
                }
            }
            LGKM0; BARRIER;
            // P1: lse over batch; wave0 folds combine tiles
            {
                int i = tid;
                int gq = i >> 3, r2 = (i & 7) * 2;
                float s = 0.f;
                #pragma unroll 8
                for (int b = 0; b < B_; ++b)
                    s += __expf((float)*(const f16*)(xp_raw + b * 512 + ((gq ^ (b & 7)) << 4) + r2));
                lse_lds[i] = __logf(s);
            }
            if (w == 0) {
                #pragma unroll
                for (int wv = 0; wv < 3; ++wv) {
                    const char* cb = smem + CMB_ACT + wv * 4096 + lane * 16;
                    #pragma unroll
                    for (int q = 0; q < 4; ++q) {
                        f32x4 v = *(const f32x4*)(cb + q * 1024);
                        accS[q*4+0] += v[0]; accS[q*4+1] += v[1];
                        accS[q*4+2] += v[2]; accS[q*4+3] += v[3];
                    }
                }
            }
            LGKM0; BARRIER;
            // P2: mean-surprisal partial dots
            {
                int b = tid >> 2, q = tid & 3;
                const float* xr = x + ((size_t)b * T_ + t) * I_ + q * 64;
                float s = 0.f;
                #pragma unroll
                for (int k = 0; k < 8; ++k) {
                    f16x8 xp8 = *(const f16x8*)(xp_raw + (size_t)b * 512 + ((((q << 3) + k) ^ (b & 7)) << 4));
                    f32x4 xa = *(const f32x4*)(xr + k * 8);
                    f32x4 xb2 = *(const f32x4*)(xr + k * 8 + 4);
                    #pragma unroll
                    for (int jj = 0; jj < 4; ++jj)
                        s += ((float)xp8[jj] - lse_lds[(q << 6) + (k << 3) + jj]) * xa[jj];
                    #pragma unroll
                    for (int jj = 0; jj < 4; ++jj)
                        s += ((float)xp8[jj + 4] - lse_lds[(q << 6) + (k << 3) + 4 + jj]) * xb2[jj];
                }
                part_lds[tid] = s;
            }
            LGKM0; BARRIER;
            // P3: gate
            if (tid < B_) {
                float s = part_lds[tid * 4] + part_lds[tid * 4 + 1] + part_lds[tid * 4 + 2] + part_lds[tid * 4 + 3];
                float mp = (s * (1.f / 256.f)) * per;
                gate_lds[tid] = 0.5f * (sinf((float)t * mp + shf) + 1.f);
                if ((a & 7) == 0) ps[((size_t)tid * T_ + t) * M_ + m] = mp;
            }
            LGKM0; BARRIER;
            // P4: wave0 blends + writes, posts own flag
            if (w == 0) {
                #pragma unroll
                for (int r = 0; r < 16; ++r) {
                    int rloc = (r & 3) + ((r >> 2) << 3) + (g << 2);
                    int row = row0 + rloc;
                    float gt = gate_lds[row];
                    float av = fast_tanh(accS[r] + bin);
                    float y = (1.f - gt) * av + gt * hreg[r];
                    hreg[r] = y;
                    st_coh_h(hnxt + (size_t)row * O_ + o0 + col, y);
                    ys[((size_t)row * T_ + t) * O_ + o0 + col] = y;
                    if (t == T_ - 1) hfin[(size_t)row * O_ + o0 + col] = y;
                }
                WAITV(0);
                if (tid == 0) st_flag(myslot, t + 1);
            }
        }
    }
}

extern "C" void kernel_launch(void* const* d_in, const int* in_sizes, int n_in,
                              void* d_out, int out_size, void* d_ws, size_t ws_size,
                              hipStream_t stream) {
    const float* x    = (const float*)d_in[0];
    const float* W_in = (const float*)d_in[1];
    const float* b_in = (const float*)d_in[2];
    const float* W_h  = (const float*)d_in[3];
    const float* W_ir = (const float*)d_in[4];
    const float* b_ir = (const float*)d_in[5];
    const float* W_hr = (const float*)d_in[6];
    const float* per  = (const float*)d_in[7];
    const float* shf  = (const float*)d_in[8];

    hipLaunchKernelGGL(init_kernel, dim3(256), dim3(256), 0, stream,
                       x, (char*)d_ws);
    hipLaunchKernelGGL(cwrnn_main, dim3(NB), dim3(THREADS), 0, stream,
                       x, W_in, b_in, W_h, W_ir, b_ir, W_hr, per, shf,
                       (float*)d_out, (char*)d_ws);
}

// Round 13
// 5308.229 us; speedup vs baseline: 1.1992x; 1.0224x over previous
//
#include <hip/hip_runtime.h>
#include <hip/hip_fp16.h>

typedef _Float16 f16;
typedef f16 f16x8 __attribute__((ext_vector_type(8)));
typedef f16 f16x4 __attribute__((ext_vector_type(4)));
typedef float f32x4 __attribute__((ext_vector_type(4)));
typedef float f32x16 __attribute__((ext_vector_type(16)));

#define B_ 64
#define T_ 512
#define I_ 256
#define O_ 1024
#define M_ 8
#define IM_ 2048
#define NRECB 128
#define NB 192
#define THREADS 256

// ws layout (bytes)
#define OFF_X16 16384ull
#define SZ_X16  16777216ull                       // [T][B][I] f16
#define OFF_XP4 (OFF_X16 + SZ_X16)                // 4 x [B][IM] f16
#define OFF_H4  (OFF_XP4 + 4ull * B_ * IM_ * 2)   // 4 x [B][O] f16

// flag slot dword indices (16B apart)
#define RECF_D(rh) (1024 + (rh) * 256)
#define ACTF_D     1536

// LDS layout
#define CMB_REC 147456
#define XPRAW   81920
#define CMB_ACT 114688
#define LSE_O   126976
#define PART_O  128000
#define GATE_O  129024
#define SMEM_SZ 159744

#define WAITV(N) asm volatile("s_waitcnt vmcnt(" #N ")" ::: "memory")
#define LGKM0    asm volatile("s_waitcnt lgkmcnt(0)" ::: "memory")
#define SCHEDB   __builtin_amdgcn_sched_barrier(0)
#define BARRIER  __builtin_amdgcn_s_barrier()

// 8 x 16B plain cached loads, 32B stride (read-only x16 input)
#define ISSUE_AX(BUF, P) asm volatile( \
    "global_load_dwordx4 %0, %8, off\n\t" \
    "global_load_dwordx4 %1, %8, off offset:32\n\t" \
    "global_load_dwordx4 %2, %8, off offset:64\n\t" \
    "global_load_dwordx4 %3, %8, off offset:96\n\t" \
    "global_load_dwordx4 %4, %8, off offset:128\n\t" \
    "global_load_dwordx4 %5, %8, off offset:160\n\t" \
    "global_load_dwordx4 %6, %8, off offset:192\n\t" \
    "global_load_dwordx4 %7, %8, off offset:224" \
    : "=&v"(abuf[BUF][0]), "=&v"(abuf[BUF][1]), "=&v"(abuf[BUF][2]), "=&v"(abuf[BUF][3]), \
      "=&v"(abuf[BUF][4]), "=&v"(abuf[BUF][5]), "=&v"(abuf[BUF][6]), "=&v"(abuf[BUF][7]) \
    : "v"(P) : "memory")

// 8 x 16B coherent (device-scope) loads, 32B stride (cross-XCD state)
#define ISSUE_AS(BUF, P) asm volatile( \
    "global_load_dwordx4 %0, %8, off sc0 sc1\n\t" \
    "global_load_dwordx4 %1, %8, off offset:32 sc0 sc1\n\t" \
    "global_load_dwordx4 %2, %8, off offset:64 sc0 sc1\n\t" \
    "global_load_dwordx4 %3, %8, off offset:96 sc0 sc1\n\t" \
    "global_load_dwordx4 %4, %8, off offset:128 sc0 sc1\n\t" \
    "global_load_dwordx4 %5, %8, off offset:160 sc0 sc1\n\t" \
    "global_load_dwordx4 %6, %8, off offset:192 sc0 sc1\n\t" \
    "global_load_dwordx4 %7, %8, off offset:224 sc0 sc1" \
    : "=&v"(abuf[BUF][0]), "=&v"(abuf[BUF][1]), "=&v"(abuf[BUF][2]), "=&v"(abuf[BUF][3]), \
      "=&v"(abuf[BUF][4]), "=&v"(abuf[BUF][5]), "=&v"(abuf[BUF][6]), "=&v"(abuf[BUF][7]) \
    : "v"(P) : "memory")

// 8 x 16B coherent loads from 8 independent addresses into named array
#define ISSUE8P(ARR, P0,P1,P2,P3,P4,P5,P6,P7) asm volatile( \
    "global_load_dwordx4 %0, %8, off sc0 sc1\n\t" \
    "global_load_dwordx4 %1, %9, off sc0 sc1\n\t" \
    "global_load_dwordx4 %2, %10, off sc0 sc1\n\t" \
    "global_load_dwordx4 %3, %11, off sc0 sc1\n\t" \
    "global_load_dwordx4 %4, %12, off sc0 sc1\n\t" \
    "global_load_dwordx4 %5, %13, off sc0 sc1\n\t" \
    "global_load_dwordx4 %6, %14, off sc0 sc1\n\t" \
    "global_load_dwordx4 %7, %15, off sc0 sc1" \
    : "=&v"((ARR)[0]), "=&v"((ARR)[1]), "=&v"((ARR)[2]), "=&v"((ARR)[3]), \
      "=&v"((ARR)[4]), "=&v"((ARR)[5]), "=&v"((ARR)[6]), "=&v"((ARR)[7]) \
    : "v"(P0), "v"(P1), "v"(P2), "v"(P3), "v"(P4), "v"(P5), "v"(P6), "v"(P7) \
    : "memory")

// one chunk: counted wait (+sched fence), 8 MFMA
#define CH(I, WN) do { \
    WAITV(WN); SCHEDB; \
    _Pragma("unroll") \
    for (int kb = 0; kb < 8; ++kb) { \
        f16x8 bf = *(const f16x8*)(smem + addrB[kb] + (I) * 256); \
        if (kb & 1) acc1 = __builtin_amdgcn_mfma_f32_32x32x16_f16(abuf[I][kb], bf, acc1, 0, 0, 0); \
        else        acc0 = __builtin_amdgcn_mfma_f32_32x32x16_f16(abuf[I][kb], bf, acc0, 0, 0, 0); \
    } \
} while (0)

__device__ __forceinline__ void st_coh_h(f16* p, float vf) {
    union { f16 h; short s; } u; u.h = (f16)vf;
    asm volatile("global_store_short %0, %1, off sc0 sc1" :: "v"(p), "v"((int)u.s) : "memory");
}

__device__ __forceinline__ float fast_tanh(float x) {
    float e = __expf(2.f * x);
    return 1.f - 2.f / (e + 1.f);
}

// raw L3-direct 4B flag read/write
__device__ __forceinline__ int ld_flag(const unsigned* p) {
    int v;
    asm volatile("global_load_dword %0, %1, off sc0 sc1" : "=v"(v) : "v"(p) : "memory");
    WAITV(0);
    return v;
}
__device__ __forceinline__ void st_flag(unsigned* p, int v) {
    asm volatile("global_store_dword %0, %1, off sc0 sc1" :: "v"(p), "v"(v) : "memory");
}

// init: zero flag region, convert x [B,T,I] f32 -> x16 [T,B,I] f16, zero state buf0
__global__ void init_kernel(const float* __restrict__ x, char* __restrict__ ws) {
    const int gid = blockIdx.x * 256 + threadIdx.x;
    if (blockIdx.x == 0) {
        for (int i = threadIdx.x; i < 4096; i += 256) ((unsigned*)ws)[i] = 0u;
    }
    f16* x16 = (f16*)(ws + OFF_X16);
    const int NQ = T_ * B_ * (I_ / 4);
    for (int q = gid; q < NQ; q += 256 * 256) {
        int t = q >> 12;
        int rem = q & 4095;
        int b = rem >> 6;
        int k4 = rem & 63;
        f32x4 v = *(const f32x4*)(x + ((size_t)b * T_ + t) * I_ + k4 * 4);
        f16x4 h;
        h[0] = (f16)v[0]; h[1] = (f16)v[1]; h[2] = (f16)v[2]; h[3] = (f16)v[3];
        *(f16x4*)(x16 + ((size_t)t * B_ + b) * I_ + k4 * 4) = h;
    }
    f16x8 z = {0, 0, 0, 0, 0, 0, 0, 0};
    f16* xp0 = (f16*)(ws + OFF_XP4);
    for (int e = gid * 8; e < B_ * IM_; e += 256 * 256 * 8) *(f16x8*)(xp0 + e) = z;
    f16* h0 = (f16*)(ws + OFF_H4);
    for (int e = gid * 8; e < B_ * O_; e += 256 * 256 * 8) *(f16x8*)(h0 + e) = z;
}

__global__ __launch_bounds__(THREADS, 1) void cwrnn_main(
    const float* __restrict__ x, const float* __restrict__ W_in, const float* __restrict__ b_in,
    const float* __restrict__ W_h, const float* __restrict__ W_ir, const float* __restrict__ b_ir,
    const float* __restrict__ W_hr, const float* __restrict__ periods, const float* __restrict__ shifts,
    float* __restrict__ out, char* __restrict__ ws)
{
    __shared__ __align__(16) char smem[SMEM_SZ];

    unsigned* bar = (unsigned*)ws;
    const int blk = blockIdx.x, tid = threadIdx.x;
    const int lane = tid & 63, w = tid >> 6;
    const int col = lane & 31, g = lane >> 5;

    float* ys = out;
    float* hfin = out + (size_t)B_ * T_ * O_;
    float* ps = hfin + (size_t)B_ * O_;

    f16* const xpB = (f16*)(ws + OFF_XP4);
    f16* h4 = (f16*)(ws + OFF_H4);

    if (blk < NRECB) {
        // ========== REC: block = (col-group cg, row-half rh); 32 rows x 32 cols ==========
        const int cg = blk >> 1, rh = blk & 1;
        const int j0 = cg * 32;
        const int row0 = rh * 32;
        const int arow = row0 + col;
        {   // stage W2 = [W_ir | W_hr] rows j0..j0+31 into swizzled LDS (once)
            const int j = tid & 31;
            const float* ra = W_ir + (size_t)(j0 + j) * I_;
            const float* rb = W_hr + (size_t)(j0 + j) * IM_ - 256;
            for (int u = (tid >> 5); u < 288; u += 8) {
                int k0 = u * 8;
                const float* s = (k0 < 256) ? (ra + k0) : (rb + k0);
                f32x4 lo = *(const f32x4*)s;
                f32x4 hi = *(const f32x4*)(s + 4);
                f16x8 v;
                #pragma unroll
                for (int e = 0; e < 4; ++e) { v[e] = (f16)lo[e]; v[e + 4] = (f16)hi[e]; }
                *(f16x8*)(smem + j * 4608 + ((u ^ (j & 15)) << 4)) = v;
            }
        }
        const float bir = b_ir[j0 + col];
        LGKM0; BARRIER;

        const int c0k = (w == 0) ? 0 : (w == 1) ? 5 : (w == 2) ? 10 : 14;
        int addrB[8];
        #pragma unroll
        for (int kb = 0; kb < 8; ++kb)
            addrB[kb] = col * 4608 + ((((kb << 1) + g) ^ (col & 15)) << 4) + c0k * 256;

        // per-lane poll target: this wave's producers only (+ ACT-slack guard on w2/w3)
        unsigned* fp = bar + RECF_D(0);
        int off = 1 << 20;
        if (w == 0)      { if (lane < 12) { fp = bar + RECF_D(rh) + lane * 4; off = 0; } }
        else if (w == 1) { if (lane < 20) { fp = bar + RECF_D(rh) + (12 + lane) * 4; off = 0; } }
        else if (w == 2) { if (lane < 16) { fp = bar + RECF_D(rh) + (32 + lane) * 4; off = 0; }
                           else if (lane < 48) { fp = bar + ACTF_D + (lane - 16) * 4; off = 2; } }
        else             { if (lane < 16) { fp = bar + RECF_D(rh) + (48 + lane) * 4; off = 0; }
                           else if (lane < 48) { fp = bar + ACTF_D + (lane + 16) * 4; off = 2; } }

        const char* xrow0 = (const char*)(ws + OFF_X16) + (size_t)arow * 512 + g * 16;
        unsigned* myslot = bar + RECF_D(rh) + cg * 4;

        for (int t = 0; t < T_ - 1; ++t) {
            // ---- wave-independent producer poll (no start barrier, no sleep) ----
            {
                int v = ld_flag(fp);
                while (__ballot(v >= t - off) != ~0ull) v = ld_flag(fp);
            }
            const int bi = t & 3, bn = (t + 1) & 3;
            const f16* xpcur = xpB + (size_t)bi * B_ * IM_;
            f16* xpnxt = xpB + (size_t)bn * B_ * IM_;
            const char* sprow = (const char*)xpcur + (size_t)arow * 4096 + g * 16 - 512;
            const char* xrow = xrow0 + (size_t)t * 32768;

            f16x8 abuf[5][8];
            f32x16 acc0, acc1;
            #pragma unroll
            for (int r = 0; r < 16; ++r) { acc0[r] = 0.f; acc1[r] = 0.f; }

            if (w == 0) {
                ISSUE_AX(0, xrow); ISSUE_AX(1, (xrow + 256));
                ISSUE_AS(2, (sprow + 2 * 256)); ISSUE_AS(3, (sprow + 3 * 256)); ISSUE_AS(4, (sprow + 4 * 256));
                CH(0, 32); CH(1, 24); CH(2, 16); CH(3, 8); CH(4, 0);
            } else if (w == 1) {
                ISSUE_AS(0, (sprow + 5 * 256)); ISSUE_AS(1, (sprow + 6 * 256)); ISSUE_AS(2, (sprow + 7 * 256));
                ISSUE_AS(3, (sprow + 8 * 256)); ISSUE_AS(4, (sprow + 9 * 256));
                CH(0, 32); CH(1, 24); CH(2, 16); CH(3, 8); CH(4, 0);
            } else if (w == 2) {
                ISSUE_AS(0, (sprow + 10 * 256)); ISSUE_AS(1, (sprow + 11 * 256));
                ISSUE_AS(2, (sprow + 12 * 256)); ISSUE_AS(3, (sprow + 13 * 256));
                CH(0, 24); CH(1, 16); CH(2, 8); CH(3, 0);
            } else {
                ISSUE_AS(0, (sprow + 14 * 256)); ISSUE_AS(1, (sprow + 15 * 256));
                ISSUE_AS(2, (sprow + 16 * 256)); ISSUE_AS(3, (sprow + 17 * 256));
                CH(0, 24); CH(1, 16); CH(2, 8); CH(3, 0);
            }

            f32x16 accS;
            #pragma unroll
            for (int r = 0; r < 16; ++r) accS[r] = acc0[r] + acc1[r];
            if (w > 0) {
                char* cb = smem + CMB_REC + (w - 1) * 4096 + lane * 16;
                #pragma unroll
                for (int q = 0; q < 4; ++q) {
                    f32x4 v = { accS[q*4+0], accS[q*4+1], accS[q*4+2], accS[q*4+3] };
                    *(f32x4*)(cb + q * 1024) = v;
                }
            }
            LGKM0; BARRIER;
            if (w == 0) {
                #pragma unroll
                for (int wv = 0; wv < 3; ++wv) {
                    const char* cb = smem + CMB_REC + wv * 4096 + lane * 16;
                    #pragma unroll
                    for (int q = 0; q < 4; ++q) {
                        f32x4 v = *(const f32x4*)(cb + q * 1024);
                        accS[q*4+0] += v[0]; accS[q*4+1] += v[1];
                        accS[q*4+2] += v[2]; accS[q*4+3] += v[3];
                    }
                }
                #pragma unroll
                for (int r = 0; r < 16; ++r) {
                    int rloc = (r & 3) + ((r >> 2) << 3) + (g << 2);
                    st_coh_h(xpnxt + (size_t)(row0 + rloc) * IM_ + j0 + col, fast_tanh(accS[r] + bir));
                }
                WAITV(0);
                if (tid == 0) st_flag(myslot, t + 1);
            }
        }
    } else {
        // ========== ACT: block = (col-group colg, row-half rh); 32 rows x 32 cols ==========
        const int a = blk - NRECB;
        const int colg = a >> 1, rh = a & 1;
        const int m = colg >> 2;
        const int o0 = colg * 32;
        const int row0 = rh * 32;
        const int arow = row0 + col;
        {   // stage W1 = [W_in | W_h] rows o0..o0+31
            const int j = tid & 31;
            const float* ra = W_in + (size_t)(o0 + j) * I_;
            const float* rb = W_h + (size_t)(o0 + j) * O_ - 256;
            for (int u = (tid >> 5); u < 160; u += 8) {
                int k0 = u * 8;
                const float* s = (k0 < 256) ? (ra + k0) : (rb + k0);
                f32x4 lo = *(const f32x4*)s;
                f32x4 hi = *(const f32x4*)(s + 4);
                f16x8 v;
                #pragma unroll
                for (int e = 0; e < 4; ++e) { v[e] = (f16)lo[e]; v[e + 4] = (f16)hi[e]; }
                *(f16x8*)(smem + j * 2560 + ((u ^ (j & 15)) << 4)) = v;
            }
        }
        const float bin = b_in[o0 + col];
        const float per = periods[m], shf = shifts[m];
        LGKM0; BARRIER;

        const int c0k = (w == 0) ? 0 : (w == 1) ? 3 : (w == 2) ? 6 : 8;
        int addrB[8];
        #pragma unroll
        for (int kb = 0; kb < 8; ++kb)
            addrB[kb] = col * 2560 + ((((kb << 1) + g) ^ (col & 15)) << 4) + c0k * 256;

        char* xp_raw = smem + XPRAW;
        float* lse_lds = (float*)(smem + LSE_O);
        float* part_lds = (float*)(smem + PART_O);
        float* gate_lds = (float*)(smem + GATE_O);

        // per-lane poll targets: own h-producers; w2/w3 add the 16 REC flags for the
        // softmax slice; w3 adds own-half ACT flags (hnxt reuse guard, off 2)
        unsigned* fp = bar + RECF_D(0);
        int off = 1 << 20;
        if (w == 0)      { if (lane < 4)  { fp = bar + ACTF_D + (rh * 32 + lane) * 4; off = 0; } }
        else if (w == 1) { if (lane < 12) { fp = bar + ACTF_D + (rh * 32 + 4 + lane) * 4; off = 0; } }
        else if (w == 2) { if (lane < 8)  { fp = bar + ACTF_D + (rh * 32 + 16 + lane) * 4; off = 0; }
                           else if (lane < 24) { int i = lane - 8; fp = bar + RECF_D(i >> 3) + (m * 8 + (i & 7)) * 4; off = 0; } }
        else             { if (lane < 8)  { fp = bar + ACTF_D + (rh * 32 + 24 + lane) * 4; off = 0; }
                           else if (lane < 24) { int i = lane - 8; fp = bar + RECF_D(i >> 3) + (m * 8 + (i & 7)) * 4; off = 0; }
                           else if (lane < 56) { fp = bar + ACTF_D + (rh * 32 + (lane - 24)) * 4; off = 2; } }

        const char* xrow0 = (const char*)(ws + OFF_X16) + (size_t)arow * 512 + g * 16;
        unsigned* myslot = bar + ACTF_D + (rh * 32 + colg) * 4;
        float hreg[16];
        #pragma unroll
        for (int r = 0; r < 16; ++r) hreg[r] = 0.f;

        const int s_ = tid - 128;
        const int cg2 = s_ & 31;
        const int r0s = (s_ >> 5) << 4;

        for (int t = 0; t < T_; ++t) {
            // ---- wave-independent producer poll ----
            {
                int v = ld_flag(fp);
                while (__ballot(v >= t - off) != ~0ull) v = ld_flag(fp);
            }
            const int bi = t & 3;
            const f16* xpcur = xpB + (size_t)bi * B_ * IM_;
            const f16* hcur = h4 + (size_t)(t & 3) * B_ * O_;
            f16* hnxt = h4 + (size_t)((t + 1) & 3) * B_ * O_;

            const char* sprow = (const char*)hcur + (size_t)arow * 2048 + g * 16 - 512;
            const char* xrow = xrow0 + (size_t)t * 32768;
            f16x8 abuf[3][8];
            f16x8 sregA[8], sregB[8];
            f32x16 acc0, acc1;
            #pragma unroll
            for (int r = 0; r < 16; ++r) { acc0[r] = 0.f; acc1[r] = 0.f; }

            if (w == 0) {
                ISSUE_AX(0, xrow); ISSUE_AX(1, (xrow + 256)); ISSUE_AS(2, (sprow + 2 * 256));
                CH(0, 16); CH(1, 8); CH(2, 0);
            } else if (w == 1) {
                ISSUE_AS(0, (sprow + 3 * 256)); ISSUE_AS(1, (sprow + 4 * 256)); ISSUE_AS(2, (sprow + 5 * 256));
                CH(0, 16); CH(1, 8); CH(2, 0);
            } else {
                const int ca = (w == 2) ? 6 : 8;
                ISSUE_AS(0, (sprow + ca * 256)); ISSUE_AS(1, (sprow + (ca + 1) * 256));
                const char* xb = (const char*)xpcur + (size_t)m * 512 + (size_t)cg2 * 16 + (size_t)r0s * 4096;
                ISSUE8P(sregA, xb, xb + 4096, xb + 2*4096, xb + 3*4096,
                               xb + 4*4096, xb + 5*4096, xb + 6*4096, xb + 7*4096);
                ISSUE8P(sregB, (xb + 8*4096), xb + 9*4096, xb + 10*4096, xb + 11*4096,
                               xb + 12*4096, xb + 13*4096, xb + 14*4096, xb + 15*4096);
                CH(0, 24); CH(1, 16);
                WAITV(0); SCHEDB;
                #pragma unroll
                for (int k = 0; k < 8; ++k) {
                    int b0 = r0s + k;
                    *(f16x8*)(xp_raw + (size_t)b0 * 512 + ((cg2 ^ (b0 & 7)) << 4)) = sregA[k];
                    int b1 = r0s + 8 + k;
                    *(f16x8*)(xp_raw + (size_t)b1 * 512 + ((cg2 ^ (b1 & 7)) << 4)) = sregB[k];
                }
            }

            f32x16 accS;
            #pragma unroll
            for (int r = 0; r < 16; ++r) accS[r] = acc0[r] + acc1[r];
            if (w > 0) {
                char* cb = smem + CMB_ACT + (w - 1) * 4096 + lane * 16;
                #pragma unroll
                for (int q = 0; q < 4; ++q) {
                    f32x4 v = { accS[q*4+0], accS[q*4+1], accS[q*4+2], accS[q*4+3] };
                    *(f32x4*)(cb + q * 1024) = v;
                }
            }
            LGKM0; BARRIER;
            // P1: lse over batch; wave0 folds combine tiles
            {
                int i = tid;
                int gq = i >> 3, r2 = (i & 7) * 2;
                float s = 0.f;
                #pragma unroll 8
                for (int b = 0; b < B_; ++b)
                    s += __expf((float)*(const f16*)(xp_raw + b * 512 + ((gq ^ (b & 7)) << 4) + r2));
                lse_lds[i] = __logf(s);
            }
            if (w == 0) {
                #pragma unroll
                for (int wv = 0; wv < 3; ++wv) {
                    const char* cb = smem + CMB_ACT + wv * 4096 + lane * 16;
                    #pragma unroll
                    for (int q = 0; q < 4; ++q) {
                        f32x4 v = *(const f32x4*)(cb + q * 1024);
                        accS[q*4+0] += v[0]; accS[q*4+1] += v[1];
                        accS[q*4+2] += v[2]; accS[q*4+3] += v[3];
                    }
                }
            }
            LGKM0; BARRIER;
            // P2: mean-surprisal partial dots
            {
                int b = tid >> 2, q = tid & 3;
                const float* xr = x + ((size_t)b * T_ + t) * I_ + q * 64;
                float s = 0.f;
                #pragma unroll
                for (int k = 0; k < 8; ++k) {
                    f16x8 xp8 = *(const f16x8*)(xp_raw + (size_t)b * 512 + ((((q << 3) + k) ^ (b & 7)) << 4));
                    f32x4 xa = *(const f32x4*)(xr + k * 8);
                    f32x4 xb2 = *(const f32x4*)(xr + k * 8 + 4);
                    #pragma unroll
                    for (int jj = 0; jj < 4; ++jj)
                        s += ((float)xp8[jj] - lse_lds[(q << 6) + (k << 3) + jj]) * xa[jj];
                    #pragma unroll
                    for (int jj = 0; jj < 4; ++jj)
                        s += ((float)xp8[jj + 4] - lse_lds[(q << 6) + (k << 3) + 4 + jj]) * xb2[jj];
                }
                part_lds[tid] = s;
            }
            LGKM0; BARRIER;
            // P3: gate
            if (tid < B_) {
                float s = part_lds[tid * 4] + part_lds[tid * 4 + 1] + part_lds[tid * 4 + 2] + part_lds[tid * 4 + 3];
                float mp = (s * (1.f / 256.f)) * per;
                gate_lds[tid] = 0.5f * (sinf((float)t * mp + shf) + 1.f);
                if ((a & 7) == 0) ps[((size_t)tid * T_ + t) * M_ + m] = mp;
            }
            LGKM0; BARRIER;
            // P4: wave0 blends; state stores -> drain -> flag; outputs AFTER flag
            if (w == 0) {
                float yv[16];
                #pragma unroll
                for (int r = 0; r < 16; ++r) {
                    int rloc = (r & 3) + ((r >> 2) << 3) + (g << 2);
                    int row = row0 + rloc;
                    float gt = gate_lds[row];
                    float av = fast_tanh(accS[r] + bin);
                    float y = (1.f - gt) * av + gt * hreg[r];
                    hreg[r] = y; yv[r] = y;
                    st_coh_h(hnxt + (size_t)row * O_ + o0 + col, y);
                }
                WAITV(0);
                if (tid == 0) st_flag(myslot, t + 1);
                #pragma unroll
                for (int r = 0; r < 16; ++r) {
                    int rloc = (r & 3) + ((r >> 2) << 3) + (g << 2);
                    int row = row0 + rloc;
                    ys[((size_t)row * T_ + t) * O_ + o0 + col] = yv[r];
                    if (t == T_ - 1) hfin[(size_t)row * O_ + o0 + col] = yv[r];
                }
            }
        }
    }
}

extern "C" void kernel_launch(void* const* d_in, const int* in_sizes, int n_in,
                              void* d_out, int out_size, void* d_ws, size_t ws_size,
                              hipStream_t stream) {
    const float* x    = (const float*)d_in[0];
    const float* W_in = (const float*)d_in[1];
    const float* b_in = (const float*)d_in[2];
    const float* W_h  = (const float*)d_in[3];
    const float* W_ir = (const float*)d_in[4];
    const float* b_ir = (const float*)d_in[5];
    const float* W_hr = (const float*)d_in[6];
    const float* per  = (const float*)d_in[7];
    const float* shf  = (const float*)d_in[8];

    hipLaunchKernelGGL(init_kernel, dim3(256), dim3(256), 0, stream,
                       x, (char*)d_ws);
    hipLaunchKernelGGL(cwrnn_main, dim3(NB), dim3(THREADS), 0, stream,
                       x, W_in, b_in, W_h, W_ir, b_ir, W_hr, per, shf,
                       (float*)d_out, (char*)d_ws);
}